// Round 5
// baseline (2715.326 us; speedup 1.0000x reference)
//
#include <hip/hip_runtime.h>
#include <math.h>

#define EPSB 1e-5f

typedef __attribute__((ext_vector_type(8))) short short8;
typedef __attribute__((ext_vector_type(4))) float floatx4;
typedef __attribute__((ext_vector_type(2))) float floatx2;

__device__ inline float bf2f(unsigned short h) {
  union { unsigned int u; float f; } v; v.u = ((unsigned int)h) << 16; return v.f;
}
__device__ inline unsigned short f2bf(float f) {
  union { float f; unsigned int u; } v; v.f = f;
  unsigned int r = v.u + 0x7fffu + ((v.u >> 16) & 1u);  // RNE
  return (unsigned short)(r >> 16);
}

// async global->LDS 16B (wave-uniform LDS base + lane*16; global addr per-lane)
__device__ __forceinline__ void gl2lds16(const unsigned short* g, unsigned short* l) {
  __builtin_amdgcn_global_load_lds(
      (const __attribute__((address_space(1))) unsigned int*)g,
      (__attribute__((address_space(3))) unsigned int*)l, 16, 0, 0);
}

// packed bf16x8 accumulate: a[j] += {lo,hi}(g[j]) * wv  via v_pk_fma_f32
__device__ __forceinline__ void pk4(floatx2* a, uint4 g, floatx2 wv) {
  unsigned int u[4] = {g.x, g.y, g.z, g.w};
#pragma unroll
  for (int j = 0; j < 4; j++) {
    union { unsigned int q; float f; } lo, hi;
    lo.q = u[j] << 16;
    hi.q = u[j] & 0xffff0000u;
    floatx2 v; v[0] = lo.f; v[1] = hi.f;
    asm("v_pk_fma_f32 %0, %1, %2, %0" : "+v"(a[j]) : "v"(v), "v"(wv));
  }
}

// ---------------- graph prep (shared by both plans) ----------------

__global__ void degcnt_kernel(const int* __restrict__ row, const int* __restrict__ col,
                              const float* __restrict__ ew,
                              float* __restrict__ deg, int* __restrict__ cnt, int E) {
  int e = blockIdx.x * blockDim.x + threadIdx.x;
  if (e < E) {
    atomicAdd(&deg[row[e]], ew[e]);
    atomicAdd(&cnt[col[e]], 1);
  }
}

__global__ void dis_kernel(float* deg, int n) {
  int i = blockIdx.x * blockDim.x + threadIdx.x;
  if (i < n) { float d = deg[i]; deg[i] = d > 0.f ? rsqrtf(d) : 0.f; }
}

// 3-phase parallel exclusive scan (blocks of 1024)
__global__ __launch_bounds__(1024) void scan1_kernel(const int* __restrict__ cnt,
                                                     int* __restrict__ off,
                                                     int* __restrict__ bsum, int n) {
  __shared__ int buf[1024];
  int tid = threadIdx.x;
  int idx = blockIdx.x * 1024 + tid;
  int v = (idx < n) ? cnt[idx] : 0;
  buf[tid] = v;
  __syncthreads();
  for (int s = 1; s < 1024; s <<= 1) {
    int t = (tid >= s) ? buf[tid - s] : 0;
    __syncthreads();
    if (tid >= s) buf[tid] += t;
    __syncthreads();
  }
  if (idx < n) off[idx] = buf[tid] - v;  // block-local exclusive
  if (tid == 1023) bsum[blockIdx.x] = buf[1023];
}

__global__ void scan2_kernel(int* __restrict__ bsum, int* __restrict__ off,
                             int nb, int n) {
  if (threadIdx.x == 0 && blockIdx.x == 0) {
    int run = 0;
    for (int k = 0; k < nb; k++) { int t = bsum[k]; bsum[k] = run; run += t; }
    off[n] = run;
  }
}

__global__ void scan3_kernel(int* __restrict__ off, const int* __restrict__ bsum, int n) {
  int i = blockIdx.x * blockDim.x + threadIdx.x;
  if (i < n) off[i] += bsum[i >> 10];
}

__global__ void copy_kernel(const int* __restrict__ src, int* __restrict__ dst, int n) {
  int i = blockIdx.x * blockDim.x + threadIdx.x;
  if (i < n) dst[i] = src[i];
}

// packed edge record: .x = source row index, .y = float bits of norm weight
__global__ void fill_kernel(const int* __restrict__ row, const int* __restrict__ col,
                            const float* __restrict__ ew, const float* __restrict__ dis,
                            int* __restrict__ wptr, int2* __restrict__ ePack, int E) {
  int e = blockIdx.x * blockDim.x + threadIdx.x;
  if (e < E) {
    int r = row[e], c = col[e];
    int p = atomicAdd(&wptr[c], 1);
    float nv = -dis[r] * ew[e] * dis[c];
    ePack[p] = make_int2(r, __float_as_int(nv));
  }
}

// ================= PLAN A (bf16 + MFMA) =================

// cast x (N x 512 fp32) into Xcat cols [0,512) (ld 1536, bf16)
__global__ void cast_x_kernel(const float* __restrict__ x, unsigned short* __restrict__ xb,
                              int N) {
  int idx = blockIdx.x * blockDim.x + threadIdx.x;
  if (idx >= N * 128) return;
  int row = idx >> 7, c4 = idx & 127;
  float4 v = *reinterpret_cast<const float4*>(x + (size_t)row * 512 + c4 * 4);
  union { unsigned int u[2]; } p;
  p.u[0] = (unsigned int)f2bf(v.x) | ((unsigned int)f2bf(v.y) << 16);
  p.u[1] = (unsigned int)f2bf(v.z) | ((unsigned int)f2bf(v.w) << 16);
  *reinterpret_cast<uint2*>(xb + (size_t)row * 1536 + c4 * 4) = make_uint2(p.u[0], p.u[1]);
}

// transpose+cast weights: W[k][n] fp32 (n fastest) -> Bt[rowOff+n][k] bf16 (ld ldBt)
__global__ void wprep_kernel(const float* __restrict__ W, unsigned short* __restrict__ Bt,
                             int Ktot, int Nout, int ldBt, int rowOff) {
  int idx = blockIdx.x * blockDim.x + threadIdx.x;
  if (idx >= Ktot * Nout) return;
  int k = idx / Nout, n = idx - k * Nout;
  Bt[(size_t)(rowOff + n) * ldBt + k] = f2bf(W[idx]);
}

// zero pad cols [1200,1216) of h1n (ld 1216) so K=1216 GEMM reads are clean
__global__ void padzero_kernel(unsigned short* __restrict__ h, int N) {
  int i = blockIdx.x * blockDim.x + threadIdx.x;
  if (i >= N * 2) return;
  *reinterpret_cast<uint4*>(h + (size_t)(i >> 1) * 1216 + 1200 + (i & 1) * 8) =
      make_uint4(0, 0, 0, 0);
}

__global__ void bcat_kernel(const float* __restrict__ a, const float* __restrict__ b,
                            const float* __restrict__ c, float* __restrict__ dst) {
  int i = threadIdx.x;
  if (i < 100) dst[i] = a[i];
  else if (i < 200) dst[i] = b[i - 100];
  else if (i < 300) dst[i] = c[i - 200];
}

// ---- layer-1 prop, L2-slice-resident ----
// 16 col-chunks of 32 (64B); grid = 2 sequential halves x ngroups x 8.
// XCD k (blockIdx%8) works cols [32k,32k+32) for the whole first half, then
// [256+32k,...): per-XCD source slice = N*64B = 3.2 MB < 4 MB L2 -> gathers
// become L2 hits after compulsory fill. Block: 256 thr = 64 nodes x 4 lanes
// of 16B. Edge offsets via shift-mul of row index (x3072 bytes).
__global__ __launch_bounds__(256) void prop_chunk_kernel(
    unsigned short* __restrict__ base,
    int srcCol, int dstCol, int subCol,    // subCol < 0 => no sub
    const int* __restrict__ off, const int2* __restrict__ eP,
    float scale, int N) {
  int ng8 = gridDim.x >> 1;
  int half = (blockIdx.x >= ng8) ? 1 : 0;
  int q = blockIdx.x - half * ng8;
  int colchunk = half * 8 + (q & 7);
  int g = q >> 3;
  int tid = threadIdx.x;
  int c4 = tid & 3;
  int v = g * 64 + (tid >> 2);
  bool valid = v < N;
  int vv = valid ? v : N - 1;
  int co = colchunk * 32 + c4 * 8;
  const char* src = (const char*)(base + srcCol + co);
  int s = off[vv], e = off[vv + 1];
  floatx2 a2[4] = {}, b2[4] = {};
  int i = s;
  for (; i + 3 < e; i += 4) {
    int2 p0 = eP[i];
    int2 p1 = eP[i + 1];
    int2 p2 = eP[i + 2];
    int2 p3 = eP[i + 3];
    unsigned o0 = ((unsigned)p0.x << 11) + ((unsigned)p0.x << 10);
    unsigned o1 = ((unsigned)p1.x << 11) + ((unsigned)p1.x << 10);
    unsigned o2 = ((unsigned)p2.x << 11) + ((unsigned)p2.x << 10);
    unsigned o3 = ((unsigned)p3.x << 11) + ((unsigned)p3.x << 10);
    uint4 g0 = *reinterpret_cast<const uint4*>(src + o0);
    uint4 g1 = *reinterpret_cast<const uint4*>(src + o1);
    uint4 g2 = *reinterpret_cast<const uint4*>(src + o2);
    uint4 g3 = *reinterpret_cast<const uint4*>(src + o3);
    floatx2 w0; w0[0] = w0[1] = __int_as_float(p0.y);
    floatx2 w1; w1[0] = w1[1] = __int_as_float(p1.y);
    floatx2 w2; w2[0] = w2[1] = __int_as_float(p2.y);
    floatx2 w3; w3[0] = w3[1] = __int_as_float(p3.y);
    pk4(a2, g0, w0);
    pk4(b2, g1, w1);
    pk4(a2, g2, w2);
    pk4(b2, g3, w3);
  }
  for (; i < e; i++) {
    int2 p = eP[i];
    unsigned o0 = ((unsigned)p.x << 11) + ((unsigned)p.x << 10);
    uint4 gg = *reinterpret_cast<const uint4*>(src + o0);
    floatx2 wv; wv[0] = wv[1] = __int_as_float(p.y);
    pk4(a2, gg, wv);
  }
  if (!valid) return;
  float a[8];
#pragma unroll
  for (int j = 0; j < 4; j++) {
    a[2 * j]     = a2[j][0] + b2[j][0];
    a[2 * j + 1] = a2[j][1] + b2[j][1];
  }
  if (subCol >= 0) {
    uint4 sv = *reinterpret_cast<const uint4*>(base + subCol + co + (size_t)v * 1536);
    a[0] = scale * a[0] - bf2f((unsigned short)(sv.x & 0xffff));
    a[1] = scale * a[1] - bf2f((unsigned short)(sv.x >> 16));
    a[2] = scale * a[2] - bf2f((unsigned short)(sv.y & 0xffff));
    a[3] = scale * a[3] - bf2f((unsigned short)(sv.y >> 16));
    a[4] = scale * a[4] - bf2f((unsigned short)(sv.z & 0xffff));
    a[5] = scale * a[5] - bf2f((unsigned short)(sv.z >> 16));
    a[6] = scale * a[6] - bf2f((unsigned short)(sv.w & 0xffff));
    a[7] = scale * a[7] - bf2f((unsigned short)(sv.w >> 16));
  }
  uint4 o;
  o.x = (unsigned int)f2bf(a[0]) | ((unsigned int)f2bf(a[1]) << 16);
  o.y = (unsigned int)f2bf(a[2]) | ((unsigned int)f2bf(a[3]) << 16);
  o.z = (unsigned int)f2bf(a[4]) | ((unsigned int)f2bf(a[5]) << 16);
  o.w = (unsigned int)f2bf(a[6]) | ((unsigned int)f2bf(a[7]) << 16);
  *reinterpret_cast<uint4*>(base + dstCol + co + (size_t)v * 1536) = o;
}

// ---- commuted layer-2 props, XCD-sliced ----
// Zcat ld 320 (40 units of 16B, 38 valid); 8 chunks x 5 units; per-XCD slice
// = 5*16B*N = 4.0 MB. Block: 320 thr = 64 nodes x 5 unit-lanes.
__global__ __launch_bounds__(320) void prop_z_kernel(
    const unsigned short* __restrict__ Zcat,
    const int* __restrict__ off, const int2* __restrict__ eP,
    float* __restrict__ h2f, unsigned short* __restrict__ U1, int N) {
  int chunk = blockIdx.x & 7;
  int g = blockIdx.x >> 3;
  int tid = threadIdx.x;
  int node = tid / 5;
  int lane = tid - node * 5;
  int v = g * 64 + node;
  int unit = chunk * 5 + lane;
  if (v >= N || unit >= 38) return;
  int s = off[v], e = off[v + 1];
  const char* srcB = (const char*)Zcat + unit * 16;
  floatx2 a2[4] = {}, b2[4] = {};
  int i = s;
  for (; i + 3 < e; i += 4) {
    int2 p0 = eP[i];
    int2 p1 = eP[i + 1];
    int2 p2 = eP[i + 2];
    int2 p3 = eP[i + 3];
    unsigned o0 = ((unsigned)p0.x << 9) + ((unsigned)p0.x << 7);  // x640
    unsigned o1 = ((unsigned)p1.x << 9) + ((unsigned)p1.x << 7);
    unsigned o2 = ((unsigned)p2.x << 9) + ((unsigned)p2.x << 7);
    unsigned o3 = ((unsigned)p3.x << 9) + ((unsigned)p3.x << 7);
    uint4 g0 = *reinterpret_cast<const uint4*>(srcB + o0);
    uint4 g1 = *reinterpret_cast<const uint4*>(srcB + o1);
    uint4 g2 = *reinterpret_cast<const uint4*>(srcB + o2);
    uint4 g3 = *reinterpret_cast<const uint4*>(srcB + o3);
    floatx2 w0; w0[0] = w0[1] = __int_as_float(p0.y);
    floatx2 w1; w1[0] = w1[1] = __int_as_float(p1.y);
    floatx2 w2; w2[0] = w2[1] = __int_as_float(p2.y);
    floatx2 w3; w3[0] = w3[1] = __int_as_float(p3.y);
    pk4(a2, g0, w0);
    pk4(b2, g1, w1);
    pk4(a2, g2, w2);
    pk4(b2, g3, w3);
  }
  for (; i < e; i++) {
    int2 p = eP[i];
    unsigned o0 = ((unsigned)p.x << 9) + ((unsigned)p.x << 7);
    uint4 raw = *reinterpret_cast<const uint4*>(srcB + o0);
    floatx2 wv; wv[0] = wv[1] = __int_as_float(p.y);
    pk4(a2, raw, wv);
  }
  float a[8];
#pragma unroll
  for (int j = 0; j < 4; j++) {
    a[2 * j]     = a2[j][0] + b2[j][0];
    a[2 * j + 1] = a2[j][1] + b2[j][1];
  }
  if (unit < 25) {
    float* p = h2f + (size_t)v * 300 + 100 + unit * 8;
#pragma unroll
    for (int j = 0; j < 8; j++) p[j] += a[j];
  } else {
    uint4 o;
    o.x = (unsigned int)f2bf(a[0]) | ((unsigned int)f2bf(a[1]) << 16);
    o.y = (unsigned int)f2bf(a[2]) | ((unsigned int)f2bf(a[3]) << 16);
    o.z = (unsigned int)f2bf(a[4]) | ((unsigned int)f2bf(a[5]) << 16);
    o.w = (unsigned int)f2bf(a[6]) | ((unsigned int)f2bf(a[7]) << 16);
    *reinterpret_cast<uint4*>(U1 + (size_t)v * 128 + (unit - 25) * 8) = o;
  }
}

// U1 ld 128 (16 units, 13 valid); 8 chunks x 2 units; slice = 1.6 MB.
// Block: 256 thr = 128 nodes x 2 unit-lanes.
__global__ __launch_bounds__(256) void prop_u_kernel(
    const unsigned short* __restrict__ U1,
    const int* __restrict__ off, const int2* __restrict__ eP,
    const unsigned short* __restrict__ Zcat, float* __restrict__ h2f, int N) {
  int chunk = blockIdx.x & 7;
  int g = blockIdx.x >> 3;
  int tid = threadIdx.x;
  int v = g * 128 + (tid >> 1);
  int unit = chunk * 2 + (tid & 1);
  if (v >= N || unit >= 13) return;
  int s = off[v], e = off[v + 1];
  const char* srcB = (const char*)U1 + unit * 16;
  floatx2 a2[4] = {}, b2[4] = {};
  int i = s;
  for (; i + 3 < e; i += 4) {
    int2 p0 = eP[i];
    int2 p1 = eP[i + 1];
    int2 p2 = eP[i + 2];
    int2 p3 = eP[i + 3];
    unsigned o0 = (unsigned)p0.x << 8;  // x256
    unsigned o1 = (unsigned)p1.x << 8;
    unsigned o2 = (unsigned)p2.x << 8;
    unsigned o3 = (unsigned)p3.x << 8;
    uint4 g0 = *reinterpret_cast<const uint4*>(srcB + o0);
    uint4 g1 = *reinterpret_cast<const uint4*>(srcB + o1);
    uint4 g2 = *reinterpret_cast<const uint4*>(srcB + o2);
    uint4 g3 = *reinterpret_cast<const uint4*>(srcB + o3);
    floatx2 w0; w0[0] = w0[1] = __int_as_float(p0.y);
    floatx2 w1; w1[0] = w1[1] = __int_as_float(p1.y);
    floatx2 w2; w2[0] = w2[1] = __int_as_float(p2.y);
    floatx2 w3; w3[0] = w3[1] = __int_as_float(p3.y);
    pk4(a2, g0, w0);
    pk4(b2, g1, w1);
    pk4(a2, g2, w2);
    pk4(b2, g3, w3);
  }
  for (; i < e; i++) {
    int2 p = eP[i];
    unsigned o0 = (unsigned)p.x << 8;
    uint4 raw = *reinterpret_cast<const uint4*>(srcB + o0);
    floatx2 wv; wv[0] = wv[1] = __int_as_float(p.y);
    pk4(a2, raw, wv);
  }
  float a[8];
#pragma unroll
  for (int j = 0; j < 4; j++) {
    a[2 * j]     = a2[j][0] + b2[j][0];
    a[2 * j + 1] = a2[j][1] + b2[j][1];
  }
  const unsigned short* z2 = Zcat + (size_t)v * 320 + 200;
  float* p = h2f + (size_t)v * 300 + 200;
#pragma unroll
  for (int j = 0; j < 8; j++) {
    int c = unit * 8 + j;
    if (c < 100) p[c] += 2.f * a[j] - bf2f(z2[c]);
  }
}

// ---- bf16 MFMA GEMM, m97 structure ----
__global__ __launch_bounds__(256) void gemm_bf16_kernel(
    const unsigned short* __restrict__ A, int lda,
    const unsigned short* __restrict__ Bt, int ldb,
    int M, int Nc, int K,
    const float* __restrict__ bias,
    unsigned short* __restrict__ Cb, float* __restrict__ Cf, int ldc, int c0,
    int accumulate) {
  __shared__ __align__(16) unsigned short As[128 * 32];
  __shared__ __align__(16) unsigned short Bs[128 * 32];
  int tid = threadIdx.x;
  int wave = tid >> 6, lane = tid & 63;
  int q = lane >> 4, mn = lane & 15;
  int wr = wave >> 1, wc = wave & 1;
  int row0 = blockIdx.y * 128, col0 = blockIdx.x * 128;
  floatx4 acc[4][4] = {};

  const unsigned short* ga[2];
  const unsigned short* gb[2];
  unsigned short* la[2];
  unsigned short* lb[2];
#pragma unroll
  for (int j = 0; j < 2; j++) {
    int c = j * 256 + tid;
    int r = c >> 2, cw = (c & 3) * 8;
    int gr = row0 + r; if (gr > M - 1) gr = M - 1;
    ga[j] = A + (size_t)gr * lda + cw;
    int gn = col0 + r; if (gn > Nc - 1) gn = Nc - 1;
    gb[j] = Bt + (size_t)gn * ldb + cw;
    la[j] = &As[(j * 256 + wave * 64) * 8];   // wave-uniform base
    lb[j] = &Bs[(j * 256 + wave * 64) * 8];
  }

  for (int k0 = 0; k0 < K; k0 += 32) {
#pragma unroll
    for (int j = 0; j < 2; j++) {
      gl2lds16(ga[j] + k0, la[j]);
      gl2lds16(gb[j] + k0, lb[j]);
    }
    __syncthreads();

    short8 af[4], bf[4];
#pragma unroll
    for (int i = 0; i < 4; i++) {
      af[i] = *reinterpret_cast<const short8*>(&As[(wr * 64 + i * 16 + mn) * 32 + q * 8]);
      bf[i] = *reinterpret_cast<const short8*>(&Bs[(wc * 64 + i * 16 + mn) * 32 + q * 8]);
    }
#pragma unroll
    for (int mi = 0; mi < 4; mi++)
#pragma unroll
      for (int ni = 0; ni < 4; ni++)
        acc[mi][ni] = __builtin_amdgcn_mfma_f32_16x16x32_bf16(af[mi], bf[ni], acc[mi][ni], 0, 0, 0);
    __syncthreads();
  }

#pragma unroll
  for (int mi = 0; mi < 4; mi++) {
#pragma unroll
    for (int ni = 0; ni < 4; ni++) {
      int gcol = col0 + wc * 64 + ni * 16 + mn;
      if (gcol >= Nc) continue;
      float b = bias ? bias[gcol] : 0.f;
#pragma unroll
      for (int r = 0; r < 4; r++) {
        int grow = row0 + wr * 64 + mi * 16 + q * 4 + r;
        if (grow >= M) continue;
        float v = acc[mi][ni][r] + b;
        if (Cb) {
          Cb[(size_t)grow * ldc + c0 + gcol] = f2bf(v);
        } else {
          float* p = Cf + (size_t)grow * ldc + c0 + gcol;
          if (accumulate) v += *p;
          *p = v;
        }
      }
    }
  }
}

// BN stats over bf16 matrix (strided)
__global__ void bn_stats_bf16_kernel(const unsigned short* __restrict__ h, int ld, int C,
                                     int N, float* __restrict__ sums) {
  int c = blockIdx.x * blockDim.x + threadIdx.x;
  if (c >= C) return;
  int r0 = blockIdx.y * 256;
  int r1 = min(N, r0 + 256);
  float s = 0.f, s2 = 0.f;
  for (int r = r0; r < r1; r++) {
    float v = bf2f(h[(size_t)r * ld + c]);
    s += v; s2 += v * v;
  }
  atomicAdd(&sums[c], s);
  atomicAdd(&sums[C + c], s2);
}

__global__ void scsh_kernel(const float* __restrict__ sums, const float* __restrict__ g,
                            const float* __restrict__ beta, float invN, int C,
                            float* __restrict__ scSh) {
  int c = blockIdx.x * blockDim.x + threadIdx.x;
  if (c >= C) return;
  float mu = sums[c] * invN;
  float var = sums[C + c] * invN - mu * mu;
  float s = rsqrtf(var + EPSB) * g[c];
  scSh[c] = s;
  scSh[C + c] = beta[c] - mu * s;
}

// BN apply (+optional relu) on bf16 matrix, 8 cols/thread
__global__ void bn_apply_bf16_kernel(unsigned short* __restrict__ h, int ld, int C8, int N,
                                     const float* __restrict__ scSh, int Cfull, int relu) {
  int idx = blockIdx.x * blockDim.x + threadIdx.x;
  if (idx >= N * C8) return;
  int row = idx / C8, c8 = idx - row * C8;
  unsigned short* p = h + (size_t)row * ld + c8 * 8;
  uint4 raw = *reinterpret_cast<uint4*>(p);
  float v[8];
  v[0] = bf2f((unsigned short)(raw.x & 0xffff)); v[1] = bf2f((unsigned short)(raw.x >> 16));
  v[2] = bf2f((unsigned short)(raw.y & 0xffff)); v[3] = bf2f((unsigned short)(raw.y >> 16));
  v[4] = bf2f((unsigned short)(raw.z & 0xffff)); v[5] = bf2f((unsigned short)(raw.z >> 16));
  v[6] = bf2f((unsigned short)(raw.w & 0xffff)); v[7] = bf2f((unsigned short)(raw.w >> 16));
#pragma unroll
  for (int j = 0; j < 8; j++) {
    int c = c8 * 8 + j;
    float o = v[j] * scSh[c] + scSh[Cfull + c];
    if (relu) o = fmaxf(o, 0.f);
    v[j] = o;
  }
  uint4 o;
  o.x = (unsigned int)f2bf(v[0]) | ((unsigned int)f2bf(v[1]) << 16);
  o.y = (unsigned int)f2bf(v[2]) | ((unsigned int)f2bf(v[3]) << 16);
  o.z = (unsigned int)f2bf(v[4]) | ((unsigned int)f2bf(v[5]) << 16);
  o.w = (unsigned int)f2bf(v[6]) | ((unsigned int)f2bf(v[7]) << 16);
  *reinterpret_cast<uint4*>(p) = o;
}

// fp32 BN pieces
__global__ void bn_stats_kernel(const float* __restrict__ h, int C, int N,
                                float* __restrict__ sums) {
  int c = blockIdx.x * blockDim.x + threadIdx.x;
  if (c >= C) return;
  int r0 = blockIdx.y * 256;
  int r1 = min(N, r0 + 256);
  float s = 0.f, s2 = 0.f;
  for (int r = r0; r < r1; r++) {
    float v = h[(size_t)r * C + c];
    s += v; s2 += v * v;
  }
  atomicAdd(&sums[c], s);
  atomicAdd(&sums[C + c], s2);
}

__global__ void bn_apply_kernel(float* __restrict__ h, int C, int N,
                                const float* __restrict__ sums, const float* __restrict__ g,
                                const float* __restrict__ beta, float invN, int relu) {
  int C4 = C >> 2;
  int c4 = blockIdx.x * blockDim.x + threadIdx.x;
  if (c4 >= C4) return;
  float sc[4], sh[4];
#pragma unroll
  for (int j = 0; j < 4; j++) {
    int c = c4 * 4 + j;
    float mu = sums[c] * invN;
    float var = sums[C + c] * invN - mu * mu;
    float s = rsqrtf(var + EPSB) * g[c];
    sc[j] = s; sh[j] = beta[c] - mu * s;
  }
  int r0 = blockIdx.y * 256, r1 = min(N, r0 + 256);
  for (int r = r0; r < r1; r++) {
    float4* p = reinterpret_cast<float4*>(h + (size_t)r * C) + c4;
    float4 v = *p;
    v.x = v.x * sc[0] + sh[0]; v.y = v.y * sc[1] + sh[1];
    v.z = v.z * sc[2] + sh[2]; v.w = v.w * sc[3] + sh[3];
    if (relu) {
      v.x = fmaxf(v.x, 0.f); v.y = fmaxf(v.y, 0.f);
      v.z = fmaxf(v.z, 0.f); v.w = fmaxf(v.w, 0.f);
    }
    *p = v;
  }
}

// ---------------- final: BN2-apply fused + linear + log_softmax ----------------

__global__ __launch_bounds__(256) void final_bn_kernel(const float* __restrict__ h2,
                                                       const float* __restrict__ scSh,
                                                       const float* __restrict__ Wl,
                                                       const float* __restrict__ bl,
                                                       float* __restrict__ out, int N) {
  __shared__ float Ws[3000];
  __shared__ float S[600];
  for (int i = threadIdx.x; i < 3000; i += 256) Ws[i] = Wl[i];
  for (int i = threadIdx.x; i < 600; i += 256) S[i] = scSh[i];
  __syncthreads();
  int r = blockIdx.x * blockDim.x + threadIdx.x;
  if (r >= N) return;
  float acc[10];
#pragma unroll
  for (int c = 0; c < 10; c++) acc[c] = bl[c];
  const float* hr = h2 + (size_t)r * 300;
  for (int k = 0; k < 300; k++) {
    float x = hr[k] * S[k] + S[300 + k];
#pragma unroll
    for (int c = 0; c < 10; c++) acc[c] += x * Ws[k * 10 + c];
  }
  float mx = acc[0];
#pragma unroll
  for (int c = 1; c < 10; c++) mx = fmaxf(mx, acc[c]);
  float se = 0.f;
#pragma unroll
  for (int c = 0; c < 10; c++) se += expf(acc[c] - mx);
  float lz = mx + logf(se);
#pragma unroll
  for (int c = 0; c < 10; c++) out[(size_t)r * 10 + c] = acc[c] - lz;
}

// plain final for Plan B
__global__ __launch_bounds__(256) void final_kernel(const float* __restrict__ h2,
                                                    const float* __restrict__ Wl,
                                                    const float* __restrict__ bl,
                                                    float* __restrict__ out, int N) {
  __shared__ float Ws[3000];
  for (int i = threadIdx.x; i < 3000; i += 256) Ws[i] = Wl[i];
  __syncthreads();
  int r = blockIdx.x * blockDim.x + threadIdx.x;
  if (r >= N) return;
  float acc[10];
#pragma unroll
  for (int c = 0; c < 10; c++) acc[c] = bl[c];
  const float* hr = h2 + (size_t)r * 300;
  for (int k = 0; k < 300; k++) {
    float x = hr[k];
#pragma unroll
    for (int c = 0; c < 10; c++) acc[c] += x * Ws[k * 10 + c];
  }
  float mx = acc[0];
#pragma unroll
  for (int c = 1; c < 10; c++) mx = fmaxf(mx, acc[c]);
  float se = 0.f;
#pragma unroll
  for (int c = 0; c < 10; c++) se += expf(acc[c] - mx);
  float lz = mx + logf(se);
#pragma unroll
  for (int c = 0; c < 10; c++) out[(size_t)r * 10 + c] = acc[c] - lz;
}

// ================= PLAN B (fp32 fallback, known-good) =================

__global__ void prop_kernel(const float* __restrict__ src, int srcLd4, int D4,
                            const int* __restrict__ off, const int2* __restrict__ ePack,
                            float* __restrict__ dst, int dstLd4,
                            const float* __restrict__ sub, int subLd4, float scale) {
  int v = blockIdx.x;
  int f4 = threadIdx.x;
  if (f4 >= D4) return;
  int s = off[v], e = off[v + 1];
  float ax = 0.f, ay = 0.f, az = 0.f, aw = 0.f;
  for (int i = s; i < e; i++) {
    int2 p = ePack[i];
    float w = __int_as_float(p.y);
    const float4 hv = *reinterpret_cast<const float4*>(src + ((size_t)p.x * srcLd4 + f4) * 4);
    ax += w * hv.x; ay += w * hv.y; az += w * hv.z; aw += w * hv.w;
  }
  float4 o;
  if (sub) {
    const float4 sv = *reinterpret_cast<const float4*>(sub + ((size_t)v * subLd4 + f4) * 4);
    o.x = scale * ax - sv.x; o.y = scale * ay - sv.y;
    o.z = scale * az - sv.z; o.w = scale * aw - sv.w;
  } else {
    o.x = ax; o.y = ay; o.z = az; o.w = aw;
  }
  *reinterpret_cast<float4*>(dst + ((size_t)v * dstLd4 + f4) * 4) = o;
}

#define BM 64
#define BN 64
#define BK 16

__global__ __launch_bounds__(256) void gemm_kernel(
    const float* __restrict__ A, int lda,
    const float* __restrict__ B, int ldb,
    float* __restrict__ C, int ldc, int c0,
    int M, int Nc, int K,
    const float* __restrict__ bias, int accumulate) {
  __shared__ float As[BK][BM + 4];
  __shared__ float Bs[BK][BN + 4];
  int tid = threadIdx.x;
  int tx = tid & 15, ty = tid >> 4;
  int row0 = blockIdx.y * BM, col0 = blockIdx.x * BN;
  float acc[4][4] = {};
  int aM = tid >> 2;
  int aK = (tid & 3) << 2;
  int bK = tid >> 4;
  int bN = (tid & 15) << 2;
  for (int k0 = 0; k0 < K; k0 += BK) {
    float4 av = make_float4(0.f, 0.f, 0.f, 0.f);
    int ar = row0 + aM;
    if (ar < M && k0 + aK < K)
      av = *reinterpret_cast<const float4*>(A + (size_t)ar * lda + k0 + aK);
    As[aK + 0][aM] = av.x; As[aK + 1][aM] = av.y;
    As[aK + 2][aM] = av.z; As[aK + 3][aM] = av.w;
    float4 bv = make_float4(0.f, 0.f, 0.f, 0.f);
    int bc = col0 + bN;
    if (bc < Nc && k0 + bK < K)
      bv = *reinterpret_cast<const float4*>(B + (size_t)(k0 + bK) * ldb + bc);
    Bs[bK][bN + 0] = bv.x; Bs[bK][bN + 1] = bv.y;
    Bs[bK][bN + 2] = bv.z; Bs[bK][bN + 3] = bv.w;
    __syncthreads();
#pragma unroll
    for (int k = 0; k < BK; k++) {
      float a0 = As[k][ty * 4 + 0], a1 = As[k][ty * 4 + 1];
      float a2 = As[k][ty * 4 + 2], a3 = As[k][ty * 4 + 3];
      float b0 = Bs[k][tx * 4 + 0], b1 = Bs[k][tx * 4 + 1];
      float b2 = Bs[k][tx * 4 + 2], b3 = Bs[k][tx * 4 + 3];
      acc[0][0] += a0 * b0; acc[0][1] += a0 * b1; acc[0][2] += a0 * b2; acc[0][3] += a0 * b3;
      acc[1][0] += a1 * b0; acc[1][1] += a1 * b1; acc[1][2] += a1 * b2; acc[1][3] += a1 * b3;
      acc[2][0] += a2 * b0; acc[2][1] += a2 * b1; acc[2][2] += a2 * b2; acc[2][3] += a2 * b3;
      acc[3][0] += a3 * b0; acc[3][1] += a3 * b1; acc[3][2] += a3 * b2; acc[3][3] += a3 * b3;
    }
    __syncthreads();
  }
#pragma unroll
  for (int i = 0; i < 4; i++) {
    int r = row0 + ty * 4 + i;
    if (r >= M) continue;
#pragma unroll
    for (int j = 0; j < 4; j++) {
      int c = col0 + tx * 4 + j;
      if (c >= Nc) continue;
      float v = acc[i][j];
      if (bias) v += bias[c];
      float* p = C + (size_t)r * ldc + c0 + c;
      if (accumulate) *p += v; else *p = v;
    }
  }
}

// ---------------- launch ----------------

extern "C" void kernel_launch(void* const* d_in, const int* in_sizes, int n_in,
                              void* d_out, int out_size, void* d_ws, size_t ws_size,
                              hipStream_t stream) {
  const float* x   = (const float*)d_in[0];
  const int*   ei  = (const int*)d_in[1];
  const float* ew  = (const float*)d_in[2];
  const float* W1a = (const float*)d_in[3];
  const float* b1a = (const float*)d_in[4];
  const float* W1b = (const float*)d_in[5];
  const float* b1b = (const float*)d_in[6];
  const float* W1c = (const float*)d_in[7];
  const float* b1c = (const float*)d_in[8];
  const float* g1  = (const float*)d_in[9];
  const float* be1 = (const float*)d_in[10];
  const float* W2a = (const float*)d_in[11];
  const float* b2a = (const float*)d_in[12];
  const float* W2b = (const float*)d_in[13];
  const float* b2b = (const float*)d_in[14];
  const float* W2c = (const float*)d_in[15];
  const float* b2c = (const float*)d_in[16];
  const float* g2  = (const float*)d_in[17];
  const float* be2 = (const float*)d_in[18];
  const float* Wl  = (const float*)d_in[19];
  const float* bl  = (const float*)d_in[20];
  float* out = (float*)d_out;

  const int N = in_sizes[0] / 512;
  const int E = in_sizes[1] / 2;
  const int* row = ei;
  const int* col = ei + E;
  (void)n_in; (void)out_size;

  int eb = (E + 255) / 256;
  int nb = (N + 255) / 256;
  int nb1 = (N + 1023) / 1024;

  // ---- common prefix layout ----
  char* ws = (char*)d_ws;
  size_t o = 0;
  int2*  ePack = (int2*)(ws + o);  o += (size_t)E * 8;
  float* dis   = (float*)(ws + o); o += (size_t)N * 4;
  int*   cnt   = (int*)(ws + o);   o += (size_t)N * 4;
  int*   off   = (int*)(ws + o);   o += (size_t)(N + 4) * 4;
  int*   wptr  = (int*)(ws + o);   o += (size_t)N * 4;
  int*   bsum  = (int*)(ws + o);   o += (size_t)(nb1 + 4) * 4;
  float* sums  = (float*)(ws + o); o += 2400 * 4;
  float* scSh  = (float*)(ws + o); o += 2400 * 4;
  float* bcat  = (float*)(ws + o); o += 304 * 4;
  o = (o + 255) & ~(size_t)255;
  size_t oCommon = o;

  // ---- plan A layout ----
  size_t oA = oCommon;
  unsigned short* Bt1a = (unsigned short*)(ws + oA); oA += (size_t)400 * 512 * 2;
  unsigned short* Bt1b = (unsigned short*)(ws + oA); oA += (size_t)400 * 1024 * 2;
  unsigned short* Bt1c = (unsigned short*)(ws + oA); oA += (size_t)400 * 1536 * 2;
  unsigned short* Bt2cat0 = (unsigned short*)(ws + oA); oA += (size_t)304 * 1216 * 2;
  unsigned short* Bt2z    = (unsigned short*)(ws + oA); oA += (size_t)304 * 1216 * 2;
  oA = (oA + 255) & ~(size_t)255;
  unsigned short* h1n = (unsigned short*)(ws + oA); oA += (size_t)N * 1216 * 2;
  oA = (oA + 255) & ~(size_t)255;
  float* h2f = (float*)(ws + oA); oA += (size_t)N * 300 * 4;
  oA = (oA + 255) & ~(size_t)255;
  // region X: Xcat (N x 1536 bf16) in phase 1; Zcat (N x 320) + U1 (N x 128) in phase 2
  unsigned short* Xcat = (unsigned short*)(ws + oA); oA += (size_t)N * 1536 * 2;
  unsigned short* Zcat = Xcat;
  unsigned short* U1 = Xcat + (size_t)N * 320;

  bool planA = (ws_size >= oA);

  // ---- graph prep (both plans) ----
  hipMemsetAsync(dis, 0, (size_t)N * 4, stream);
  hipMemsetAsync(cnt, 0, (size_t)N * 4, stream);
  degcnt_kernel<<<eb, 256, 0, stream>>>(row, col, ew, dis, cnt, E);
  dis_kernel<<<nb, 256, 0, stream>>>(dis, N);
  scan1_kernel<<<nb1, 1024, 0, stream>>>(cnt, off, bsum, N);
  scan2_kernel<<<1, 64, 0, stream>>>(bsum, off, nb1, N);
  scan3_kernel<<<nb, 256, 0, stream>>>(off, bsum, N);
  copy_kernel<<<nb, 256, 0, stream>>>(off, wptr, N);
  fill_kernel<<<eb, 256, 0, stream>>>(row, col, ew, dis, wptr, ePack, E);

  if (planA) {
    // weight prep + x cast
    wprep_kernel<<<(400 * 512 + 255) / 256, 256, 0, stream>>>(W1a, Bt1a, 512, 400, 512, 0);
    wprep_kernel<<<(400 * 1024 + 255) / 256, 256, 0, stream>>>(W1b, Bt1b, 1024, 400, 1024, 0);
    wprep_kernel<<<(400 * 1536 + 255) / 256, 256, 0, stream>>>(W1c, Bt1c, 1536, 400, 1536, 0);
    // layer-2 weights at ldb=1216 (K padded 1200->1216); memset keeps pad cols zero
    hipMemsetAsync(Bt2cat0, 0, (size_t)304 * 1216 * 2, stream);
    hipMemsetAsync(Bt2z, 0, (size_t)304 * 1216 * 2, stream);
    wprep_kernel<<<(100 * 1200 + 255) / 256, 256, 0, stream>>>(W2a, Bt2cat0, 1200, 100, 1216, 0);
    wprep_kernel<<<(100 * 1200 + 255) / 256, 256, 0, stream>>>(W2b, Bt2cat0, 1200, 100, 1216, 100);
    wprep_kernel<<<(100 * 1200 + 255) / 256, 256, 0, stream>>>(W2c, Bt2cat0, 1200, 100, 1216, 200);
    wprep_kernel<<<(100 * 1200 + 255) / 256, 256, 0, stream>>>(W2b + 1200 * 100, Bt2z, 1200, 100, 1216, 0);
    wprep_kernel<<<(100 * 1200 + 255) / 256, 256, 0, stream>>>(W2c + 1200 * 100, Bt2z, 1200, 100, 1216, 100);
    wprep_kernel<<<(100 * 1200 + 255) / 256, 256, 0, stream>>>(W2c + 2 * 1200 * 100, Bt2z, 1200, 100, 1216, 200);
    bcat_kernel<<<1, 320, 0, stream>>>(b2a, b2b, b2c, bcat);
    cast_x_kernel<<<(N * 128 + 255) / 256, 256, 0, stream>>>(x, Xcat, N);
    padzero_kernel<<<(N * 2 + 255) / 256, 256, 0, stream>>>(h1n, N);

    // layer-1 props (L2-slice-resident): P1 = L x ; P2 = 2 L P1 - x
    int ng64 = (N + 63) / 64;
    prop_chunk_kernel<<<ng64 * 16, 256, 0, stream>>>(Xcat, 0, 512, -1, off, ePack, 1.f, N);
    prop_chunk_kernel<<<ng64 * 16, 256, 0, stream>>>(Xcat, 512, 1024, 0, off, ePack, 2.f, N);

    // layer-1 GEMMs -> h1n (bf16, ld 1216)
    dim3 gA((400 + 127) / 128, (N + 127) / 128);
    gemm_bf16_kernel<<<gA, 256, 0, stream>>>(Xcat, 1536, Bt1a, 512, N, 400, 512,
                                             b1a, h1n, nullptr, 1216, 0, 0);
    gemm_bf16_kernel<<<gA, 256, 0, stream>>>(Xcat, 1536, Bt1b, 1024, N, 400, 1024,
                                             b1b, h1n, nullptr, 1216, 400, 0);
    gemm_bf16_kernel<<<gA, 256, 0, stream>>>(Xcat, 1536, Bt1c, 1536, N, 400, 1536,
                                             b1c, h1n, nullptr, 1216, 800, 0);

    // BN1 + ReLU on h1n
    hipMemsetAsync(sums, 0, 2400 * 4, stream);
    dim3 s1g((1200 + 255) / 256, (N + 255) / 256);
    bn_stats_bf16_kernel<<<s1g, 256, 0, stream>>>(h1n, 1216, 1200, N, sums);
    scsh_kernel<<<(1200 + 255) / 256, 256, 0, stream>>>(sums, g1, be1, 1.f / (float)N, 1200, scSh);
    bn_apply_bf16_kernel<<<((size_t)N * 150 + 255) / 256, 256, 0, stream>>>(
        h1n, 1216, 150, N, scSh, 1200, 1);

    // layer-2 GEMM 1: h2f = h1n*[W2a|W2b0|W2c0] + bias (fp32, 300 cols), K=1216
    dim3 gB0((300 + 127) / 128, (N + 127) / 128);
    gemm_bf16_kernel<<<gB0, 256, 0, stream>>>(h1n, 1216, Bt2cat0, 1216, N, 300, 1216,
                                              bcat, nullptr, h2f, 300, 0, 0);

    // layer-2 GEMM 2: Zcat = h1n*[W2b1|W2c1|W2c2|0] -> bf16 (304 cols, ld 320), K=1216
    dim3 gBz((304 + 127) / 128, (N + 127) / 128);
    gemm_bf16_kernel<<<gBz, 256, 0, stream>>>(h1n, 1216, Bt2z, 1216, N, 304, 1216,
                                              nullptr, Zcat, nullptr, 320, 0, 0);

    // commuted props (XCD-sliced)
    prop_z_kernel<<<ng64 * 8, 320, 0, stream>>>(Zcat, off, ePack, h2f, U1, N);
    int ng128 = (N + 127) / 128;
    prop_u_kernel<<<ng128 * 8, 256, 0, stream>>>(U1, off, ePack, Zcat, h2f, N);

    // BN2 stats -> scSh; apply fused into final
    hipMemsetAsync(sums, 0, 2400 * 4, stream);
    dim3 s2g((300 + 255) / 256, (N + 255) / 256);
    bn_stats_kernel<<<s2g, 256, 0, stream>>>(h2f, 300, N, sums);
    scsh_kernel<<<(300 + 255) / 256, 256, 0, stream>>>(sums, g2, be2, 1.f / (float)N, 300, scSh);
    final_bn_kernel<<<nb, 256, 0, stream>>>(h2f, scSh, Wl, bl, out, N);
    return;
  }

  // ================= PLAN B (fp32 fallback) =================
  size_t oB = oCommon;
  float* h2 = (float*)(ws + oB); oB += (size_t)N * 300 * 4;
  oB = (oB + 255) & ~(size_t)255;
  float* h1 = (float*)(ws + oB); oB += (size_t)N * 1200 * 4;
  oB = (oB + 255) & ~(size_t)255;
  size_t avail = (ws_size > oB) ? (ws_size - oB) : 0;
  int C1 = 64;
  { const int opts[4] = {512, 256, 128, 64};
    for (int i = 0; i < 4; i++)
      if ((size_t)2 * N * opts[i] * 4 <= avail) { C1 = opts[i]; break; } }
  int C2 = 100;
  { const int opts[6] = {1200, 600, 400, 300, 200, 100};
    for (int i = 0; i < 6; i++)
      if ((size_t)2 * N * opts[i] * 4 <= avail) { C2 = opts[i]; break; } }
  int maxC = C1 > C2 ? C1 : C2;
  float* S1 = (float*)(ws + oB);
  float* S2 = S1 + (size_t)N * maxC;

  dim3 g1d((400 + BN - 1) / BN, (N + BM - 1) / BM);
  gemm_kernel<<<g1d, 256, 0, stream>>>(x, 512, W1a, 400, h1, 1200, 0,   N, 400, 512, b1a, 0);
  gemm_kernel<<<g1d, 256, 0, stream>>>(x, 512, W1b, 400, h1, 1200, 400, N, 400, 512, b1b, 0);
  gemm_kernel<<<g1d, 256, 0, stream>>>(x, 512, W1c, 400, h1, 1200, 800, N, 400, 512, b1c, 0);
  for (int c = 0; c < 512; c += C1) {
    int D4 = C1 / 4;
    int bt = ((D4 + 63) / 64) * 64;
    prop_kernel<<<N, bt, 0, stream>>>(x + c, 128, D4, off, ePack, S1, D4, nullptr, 0, 1.f);
    gemm_kernel<<<g1d, 256, 0, stream>>>(S1, C1, W1b + (size_t)(512 + c) * 400, 400, h1, 1200, 400, N, 400, C1, nullptr, 1);
    gemm_kernel<<<g1d, 256, 0, stream>>>(S1, C1, W1c + (size_t)(512 + c) * 400, 400, h1, 1200, 800, N, 400, C1, nullptr, 1);
    prop_kernel<<<N, bt, 0, stream>>>(S1, D4, D4, off, ePack, S2, D4, x + c, 128, 2.f);
    gemm_kernel<<<g1d, 256, 0, stream>>>(S2, C1, W1c + (size_t)(2 * 512 + c) * 400, 400, h1, 1200, 800, N, 400, C1, nullptr, 1);
  }

  hipMemsetAsync(sums, 0, 2400 * 4, stream);
  dim3 s1g((1200 + 255) / 256, (N + 255) / 256);
  bn_stats_kernel<<<s1g, 256, 0, stream>>>(h1, 1200, N, sums);
  dim3 a1g((300 + 63) / 64, (N + 255) / 256);
  bn_apply_kernel<<<a1g, 64, 0, stream>>>(h1, 1200, N, sums, g1, be1, 1.f / (float)N, 1);

  dim3 g2d((100 + BN - 1) / BN, (N + BM - 1) / BM);
  gemm_kernel<<<g2d, 256, 0, stream>>>(h1, 1200, W2a, 100, h2, 300, 0,   N, 100, 1200, b2a, 0);
  gemm_kernel<<<g2d, 256, 0, stream>>>(h1, 1200, W2b, 100, h2, 300, 100, N, 100, 1200, b2b, 0);
  gemm_kernel<<<g2d, 256, 0, stream>>>(h1, 1200, W2c, 100, h2, 300, 200, N, 100, 1200, b2c, 0);
  for (int c = 0; c < 1200; c += C2) {
    int D4 = C2 / 4;
    int bt = ((D4 + 63) / 64) * 64;
    prop_kernel<<<N, bt, 0, stream>>>(h1 + c, 300, D4, off, ePack, S1, D4, nullptr, 0, 1.f);
    gemm_kernel<<<g2d, 256, 0, stream>>>(S1, C2, W2b + (size_t)(1200 + c) * 100, 100, h2, 300, 100, N, 100, C2, nullptr, 1);
    gemm_kernel<<<g2d, 256, 0, stream>>>(S1, C2, W2c + (size_t)(1200 + c) * 100, 100, h2, 300, 200, N, 100, C2, nullptr, 1);
    prop_kernel<<<N, bt, 0, stream>>>(S1, D4, D4, off, ePack, S2, D4, h1 + c, 300, 2.f);
    gemm_kernel<<<g2d, 256, 0, stream>>>(S2, C2, W2c + (size_t)(2 * 1200 + c) * 100, 100, h2, 300, 200, N, 100, C2, nullptr, 1);
  }

  hipMemsetAsync(sums, 0, 2400 * 4, stream);
  dim3 s2g((300 + 255) / 256, (N + 255) / 256);
  bn_stats_kernel<<<s2g, 256, 0, stream>>>(h2, 300, N, sums);
  dim3 a2g((75 + 63) / 64, (N + 255) / 256);
  bn_apply_kernel<<<a2g, 64, 0, stream>>>(h2, 300, N, sums, g2, be2, 1.f / (float)N, 0);

  final_kernel<<<nb, 256, 0, stream>>>(h2, Wl, bl, out, N);
}

// Round 6
// 1790.784 us; speedup vs baseline: 1.5163x; 1.5163x over previous
//
#include <hip/hip_runtime.h>
#include <math.h>

#define EPSB 1e-5f

typedef __attribute__((ext_vector_type(8))) short short8;
typedef __attribute__((ext_vector_type(4))) float floatx4;
typedef __attribute__((ext_vector_type(2))) float floatx2;

__device__ inline float bf2f(unsigned short h) {
  union { unsigned int u; float f; } v; v.u = ((unsigned int)h) << 16; return v.f;
}
__device__ inline unsigned short f2bf(float f) {
  union { float f; unsigned int u; } v; v.f = f;
  unsigned int r = v.u + 0x7fffu + ((v.u >> 16) & 1u);  // RNE
  return (unsigned short)(r >> 16);
}

// async global->LDS 16B (wave-uniform LDS base + lane*16; global addr per-lane)
__device__ __forceinline__ void gl2lds16(const unsigned short* g, unsigned short* l) {
  __builtin_amdgcn_global_load_lds(
      (const __attribute__((address_space(1))) unsigned int*)g,
      (__attribute__((address_space(3))) unsigned int*)l, 16, 0, 0);
}

// packed bf16x8 accumulate: a[j] += {lo,hi}(g[j]) * wv  via v_pk_fma_f32
__device__ __forceinline__ void pk4(floatx2* a, uint4 g, floatx2 wv) {
  unsigned int u[4] = {g.x, g.y, g.z, g.w};
#pragma unroll
  for (int j = 0; j < 4; j++) {
    union { unsigned int q; float f; } lo, hi;
    lo.q = u[j] << 16;
    hi.q = u[j] & 0xffff0000u;
    floatx2 v; v[0] = lo.f; v[1] = hi.f;
    asm("v_pk_fma_f32 %0, %1, %2, %0" : "+v"(a[j]) : "v"(v), "v"(wv));
  }
}

// ---------------- graph prep (shared by both plans) ----------------

// fused degree-sum (by row) + in-degree count (by col), one edge pass
__global__ void degcnt_kernel(const int* __restrict__ row, const int* __restrict__ col,
                              const float* __restrict__ ew,
                              float* __restrict__ deg, int* __restrict__ cnt, int E) {
  int e = blockIdx.x * blockDim.x + threadIdx.x;
  if (e < E) {
    atomicAdd(&deg[row[e]], ew[e]);
    atomicAdd(&cnt[col[e]], 1);
  }
}

__global__ void dis_kernel(float* deg, int n) {
  int i = blockIdx.x * blockDim.x + threadIdx.x;
  if (i < n) { float d = deg[i]; deg[i] = d > 0.f ? rsqrtf(d) : 0.f; }
}

// 3-phase parallel exclusive scan (blocks of 1024)
__global__ __launch_bounds__(1024) void scan1_kernel(const int* __restrict__ cnt,
                                                     int* __restrict__ off,
                                                     int* __restrict__ bsum, int n) {
  __shared__ int buf[1024];
  int tid = threadIdx.x;
  int idx = blockIdx.x * 1024 + tid;
  int v = (idx < n) ? cnt[idx] : 0;
  buf[tid] = v;
  __syncthreads();
  for (int s = 1; s < 1024; s <<= 1) {
    int t = (tid >= s) ? buf[tid - s] : 0;
    __syncthreads();
    if (tid >= s) buf[tid] += t;
    __syncthreads();
  }
  if (idx < n) off[idx] = buf[tid] - v;  // block-local exclusive
  if (tid == 1023) bsum[blockIdx.x] = buf[1023];
}

__global__ void scan2_kernel(int* __restrict__ bsum, int* __restrict__ off,
                             int nb, int n) {
  if (threadIdx.x == 0 && blockIdx.x == 0) {
    int run = 0;
    for (int k = 0; k < nb; k++) { int t = bsum[k]; bsum[k] = run; run += t; }
    off[n] = run;
  }
}

__global__ void scan3_kernel(int* __restrict__ off, const int* __restrict__ bsum, int n) {
  int i = blockIdx.x * blockDim.x + threadIdx.x;
  if (i < n) off[i] += bsum[i >> 10];
}

__global__ void copy_kernel(const int* __restrict__ src, int* __restrict__ dst, int n) {
  int i = blockIdx.x * blockDim.x + threadIdx.x;
  if (i < n) dst[i] = src[i];
}

// packed edge record: .x = source row index, .y = float bits of norm weight
__global__ void fill_kernel(const int* __restrict__ row, const int* __restrict__ col,
                            const float* __restrict__ ew, const float* __restrict__ dis,
                            int* __restrict__ wptr, int2* __restrict__ ePack, int E) {
  int e = blockIdx.x * blockDim.x + threadIdx.x;
  if (e < E) {
    int r = row[e], c = col[e];
    int p = atomicAdd(&wptr[c], 1);
    float nv = -dis[r] * ew[e] * dis[c];
    ePack[p] = make_int2(r, __float_as_int(nv));
  }
}

// ================= PLAN A (bf16 + MFMA) =================

// cast x (N x 512 fp32) into Xcat cols [0,512) (ld 1536, bf16)
__global__ void cast_x_kernel(const float* __restrict__ x, unsigned short* __restrict__ xb,
                              int N) {
  int idx = blockIdx.x * blockDim.x + threadIdx.x;
  if (idx >= N * 128) return;
  int row = idx >> 7, c4 = idx & 127;
  float4 v = *reinterpret_cast<const float4*>(x + (size_t)row * 512 + c4 * 4);
  union { unsigned int u[2]; } p;
  p.u[0] = (unsigned int)f2bf(v.x) | ((unsigned int)f2bf(v.y) << 16);
  p.u[1] = (unsigned int)f2bf(v.z) | ((unsigned int)f2bf(v.w) << 16);
  *reinterpret_cast<uint2*>(xb + (size_t)row * 1536 + c4 * 4) = make_uint2(p.u[0], p.u[1]);
}

// transpose+cast weights: W[k][n] fp32 (n fastest) -> Bt[rowOff+n][k] bf16 (ld ldBt)
__global__ void wprep_kernel(const float* __restrict__ W, unsigned short* __restrict__ Bt,
                             int Ktot, int Nout, int ldBt, int rowOff) {
  int idx = blockIdx.x * blockDim.x + threadIdx.x;
  if (idx >= Ktot * Nout) return;
  int k = idx / Nout, n = idx - k * Nout;
  Bt[(size_t)(rowOff + n) * ldBt + k] = f2bf(W[idx]);
}

// zero pad cols [1200,1216) of h1n (ld 1216) so K=1216 GEMM reads are clean
__global__ void padzero_kernel(unsigned short* __restrict__ h, int N) {
  int i = blockIdx.x * blockDim.x + threadIdx.x;
  if (i >= N * 2) return;
  *reinterpret_cast<uint4*>(h + (size_t)(i >> 1) * 1216 + 1200 + (i & 1) * 8) =
      make_uint4(0, 0, 0, 0);
}

__global__ void bcat_kernel(const float* __restrict__ a, const float* __restrict__ b,
                            const float* __restrict__ c, float* __restrict__ dst) {
  int i = threadIdx.x;
  if (i < 100) dst[i] = a[i];
  else if (i < 200) dst[i] = b[i - 100];
  else if (i < 300) dst[i] = c[i - 200];
}

// ---- XCD-affine chunked layer-1 prop (R2/R3-benched version: 177 us, its
// mixed L2/L3/HBM service floor — do not touch) ----
// 8 col-chunks of 64; chunk = blockIdx.x & 7 rides round-robin XCD dispatch.
// Block: 256 thr = 8 nodes x (4 edge-slots x 8 col-threads of 16B).
// Each slot owns a CONTIGUOUS quarter of the node's edge range.
__global__ __launch_bounds__(256) void prop_chunk_kernel(
    unsigned short* __restrict__ base, int ld,
    int srcCol, int dstCol, int subCol,    // subCol < 0 => no sub
    const int* __restrict__ off, const int2* __restrict__ ePack,
    float scale, int N) {
  int chunk = blockIdx.x & 7;
  int g = blockIdx.x >> 3;
  int tid = threadIdx.x;
  int slot = (tid >> 3) & 3;
  int c8 = tid & 7;
  int v = g * 8 + (tid >> 5);
  bool valid = v < N;
  int vv = valid ? v : N - 1;
  int co = chunk * 64 + c8 * 8;
  const unsigned short* src = base + srcCol + co;
  int s = off[vv], e = off[vv + 1];
  int len = e - s;
  int s0 = s + (len * slot >> 2);
  int e0 = s + (len * (slot + 1) >> 2);
  floatx2 a2[4] = {}, b2[4] = {};
  int i = s0;
  for (; i + 3 < e0; i += 4) {
    int2 p0 = ePack[i];
    int2 p1 = ePack[i + 1];
    int2 p2 = ePack[i + 2];
    int2 p3 = ePack[i + 3];
    uint4 g0 = *reinterpret_cast<const uint4*>(src + (size_t)p0.x * ld);
    uint4 g1 = *reinterpret_cast<const uint4*>(src + (size_t)p1.x * ld);
    uint4 g2 = *reinterpret_cast<const uint4*>(src + (size_t)p2.x * ld);
    uint4 g3 = *reinterpret_cast<const uint4*>(src + (size_t)p3.x * ld);
    floatx2 w0; w0[0] = w0[1] = __int_as_float(p0.y);
    floatx2 w1; w1[0] = w1[1] = __int_as_float(p1.y);
    floatx2 w2; w2[0] = w2[1] = __int_as_float(p2.y);
    floatx2 w3; w3[0] = w3[1] = __int_as_float(p3.y);
    pk4(a2, g0, w0);
    pk4(b2, g1, w1);
    pk4(a2, g2, w2);
    pk4(b2, g3, w3);
  }
  for (; i < e0; i++) {
    int2 p = ePack[i];
    uint4 gg = *reinterpret_cast<const uint4*>(src + (size_t)p.x * ld);
    floatx2 wv; wv[0] = wv[1] = __int_as_float(p.y);
    pk4(a2, gg, wv);
  }
  float a[8];
#pragma unroll
  for (int j = 0; j < 4; j++) {
    a[2 * j]     = a2[j][0] + b2[j][0];
    a[2 * j + 1] = a2[j][1] + b2[j][1];
  }
  // reduce across the 4 edge-slots (lane bits 3,4 — stays in each node's 32 lanes)
#pragma unroll
  for (int j = 0; j < 8; j++) {
    a[j] += __shfl_xor(a[j], 8);
    a[j] += __shfl_xor(a[j], 16);
  }
  if (slot != 0 || !valid) return;
  if (subCol >= 0) {
    uint4 sv = *reinterpret_cast<const uint4*>(base + subCol + co + (size_t)v * ld);
    a[0] = scale * a[0] - bf2f((unsigned short)(sv.x & 0xffff));
    a[1] = scale * a[1] - bf2f((unsigned short)(sv.x >> 16));
    a[2] = scale * a[2] - bf2f((unsigned short)(sv.y & 0xffff));
    a[3] = scale * a[3] - bf2f((unsigned short)(sv.y >> 16));
    a[4] = scale * a[4] - bf2f((unsigned short)(sv.z & 0xffff));
    a[5] = scale * a[5] - bf2f((unsigned short)(sv.z >> 16));
    a[6] = scale * a[6] - bf2f((unsigned short)(sv.w & 0xffff));
    a[7] = scale * a[7] - bf2f((unsigned short)(sv.w >> 16));
  }
  uint4 o;
  o.x = (unsigned int)f2bf(a[0]) | ((unsigned int)f2bf(a[1]) << 16);
  o.y = (unsigned int)f2bf(a[2]) | ((unsigned int)f2bf(a[3]) << 16);
  o.z = (unsigned int)f2bf(a[4]) | ((unsigned int)f2bf(a[5]) << 16);
  o.w = (unsigned int)f2bf(a[6]) | ((unsigned int)f2bf(a[7]) << 16);
  *reinterpret_cast<uint4*>(base + dstCol + co + (size_t)v * ld) = o;
}

// ---- commuted layer-2 props (unroll-4 MLP + pk_fma; R3-benched) ----
__global__ void prop_z_kernel(const unsigned short* __restrict__ Zcat,
                              const int* __restrict__ off, const int2* __restrict__ ePack,
                              float* __restrict__ h2f, unsigned short* __restrict__ U1) {
  int v = blockIdx.x;
  int f8 = threadIdx.x;
  if (f8 >= 38) return;
  int s = off[v], e = off[v + 1];
  floatx2 a2[4] = {}, b2[4] = {};
  int i = s;
  for (; i + 3 < e; i += 4) {
    int2 p0 = ePack[i];
    int2 p1 = ePack[i + 1];
    int2 p2 = ePack[i + 2];
    int2 p3 = ePack[i + 3];
    uint4 g0 = *reinterpret_cast<const uint4*>(Zcat + (size_t)p0.x * 304 + f8 * 8);
    uint4 g1 = *reinterpret_cast<const uint4*>(Zcat + (size_t)p1.x * 304 + f8 * 8);
    uint4 g2 = *reinterpret_cast<const uint4*>(Zcat + (size_t)p2.x * 304 + f8 * 8);
    uint4 g3 = *reinterpret_cast<const uint4*>(Zcat + (size_t)p3.x * 304 + f8 * 8);
    floatx2 w0; w0[0] = w0[1] = __int_as_float(p0.y);
    floatx2 w1; w1[0] = w1[1] = __int_as_float(p1.y);
    floatx2 w2; w2[0] = w2[1] = __int_as_float(p2.y);
    floatx2 w3; w3[0] = w3[1] = __int_as_float(p3.y);
    pk4(a2, g0, w0);
    pk4(b2, g1, w1);
    pk4(a2, g2, w2);
    pk4(b2, g3, w3);
  }
  for (; i < e; i++) {
    int2 p = ePack[i];
    uint4 raw = *reinterpret_cast<const uint4*>(Zcat + (size_t)p.x * 304 + f8 * 8);
    floatx2 wv; wv[0] = wv[1] = __int_as_float(p.y);
    pk4(a2, raw, wv);
  }
  float a[8];
#pragma unroll
  for (int j = 0; j < 4; j++) {
    a[2 * j]     = a2[j][0] + b2[j][0];
    a[2 * j + 1] = a2[j][1] + b2[j][1];
  }
  if (f8 < 25) {
    float* p = h2f + (size_t)v * 300 + 100 + f8 * 8;
#pragma unroll
    for (int j = 0; j < 8; j++) p[j] += a[j];
  } else {
    uint4 o;
    o.x = (unsigned int)f2bf(a[0]) | ((unsigned int)f2bf(a[1]) << 16);
    o.y = (unsigned int)f2bf(a[2]) | ((unsigned int)f2bf(a[3]) << 16);
    o.z = (unsigned int)f2bf(a[4]) | ((unsigned int)f2bf(a[5]) << 16);
    o.w = (unsigned int)f2bf(a[6]) | ((unsigned int)f2bf(a[7]) << 16);
    *reinterpret_cast<uint4*>(U1 + (size_t)v * 104 + (f8 - 25) * 8) = o;
  }
}

__global__ void prop_u_kernel(const unsigned short* __restrict__ U1,
                              const int* __restrict__ off, const int2* __restrict__ ePack,
                              const unsigned short* __restrict__ Zcat,
                              float* __restrict__ h2f) {
  int v = blockIdx.x;
  int f8 = threadIdx.x;
  if (f8 >= 13) return;
  int s = off[v], e = off[v + 1];
  floatx2 a2[4] = {}, b2[4] = {};
  int i = s;
  for (; i + 3 < e; i += 4) {
    int2 p0 = ePack[i];
    int2 p1 = ePack[i + 1];
    int2 p2 = ePack[i + 2];
    int2 p3 = ePack[i + 3];
    uint4 g0 = *reinterpret_cast<const uint4*>(U1 + (size_t)p0.x * 104 + f8 * 8);
    uint4 g1 = *reinterpret_cast<const uint4*>(U1 + (size_t)p1.x * 104 + f8 * 8);
    uint4 g2 = *reinterpret_cast<const uint4*>(U1 + (size_t)p2.x * 104 + f8 * 8);
    uint4 g3 = *reinterpret_cast<const uint4*>(U1 + (size_t)p3.x * 104 + f8 * 8);
    floatx2 w0; w0[0] = w0[1] = __int_as_float(p0.y);
    floatx2 w1; w1[0] = w1[1] = __int_as_float(p1.y);
    floatx2 w2; w2[0] = w2[1] = __int_as_float(p2.y);
    floatx2 w3; w3[0] = w3[1] = __int_as_float(p3.y);
    pk4(a2, g0, w0);
    pk4(b2, g1, w1);
    pk4(a2, g2, w2);
    pk4(b2, g3, w3);
  }
  for (; i < e; i++) {
    int2 p = ePack[i];
    uint4 raw = *reinterpret_cast<const uint4*>(U1 + (size_t)p.x * 104 + f8 * 8);
    floatx2 wv; wv[0] = wv[1] = __int_as_float(p.y);
    pk4(a2, raw, wv);
  }
  float a[8];
#pragma unroll
  for (int j = 0; j < 4; j++) {
    a[2 * j]     = a2[j][0] + b2[j][0];
    a[2 * j + 1] = a2[j][1] + b2[j][1];
  }
  const unsigned short* z2 = Zcat + (size_t)v * 304 + 200;
  float* p = h2f + (size_t)v * 300 + 200;
#pragma unroll
  for (int j = 0; j < 8; j++) {
    int c = f8 * 8 + j;
    if (c < 100) p[c] += 2.f * a[j] - bf2f(z2[c]);
  }
}

// ---- bf16 MFMA GEMM, m97 structure + XCD row-affine block remap ----
// 1D grid; XCD k (linear%8) owns a contiguous run of ROW tiles with all
// col-tiles of a row on the same XCD (consecutive slots differ by 8 in linear
// id -> same XCD under round-robin dispatch). The 128xK A-panel then loads
// into ONE L2 instead of one per col-tile's XCD (A traffic / ~colTiles).
__global__ __launch_bounds__(256) void gemm_bf16_kernel(
    const unsigned short* __restrict__ A, int lda,
    const unsigned short* __restrict__ Bt, int ldb,
    int M, int Nc, int K,
    const float* __restrict__ bias,
    unsigned short* __restrict__ Cb, float* __restrict__ Cf, int ldc, int c0,
    int accumulate) {
  __shared__ __align__(16) unsigned short As[128 * 32];
  __shared__ __align__(16) unsigned short Bs[128 * 32];
  int colTiles = (Nc + 127) >> 7;
  int rowTiles = (M + 127) >> 7;
  int L = blockIdx.x;
  int xcd = L & 7, slot = L >> 3;
  int rpx = (rowTiles + 7) >> 3;
  int rloc = slot / colTiles;
  int ct = slot - rloc * colTiles;
  int rt = xcd * rpx + rloc;
  if (rt >= rowTiles) return;
  int row0 = rt << 7, col0 = ct << 7;

  int tid = threadIdx.x;
  int wave = tid >> 6, lane = tid & 63;
  int q = lane >> 4, mn = lane & 15;
  int wr = wave >> 1, wc = wave & 1;
  floatx4 acc[4][4] = {};

  const unsigned short* ga[2];
  const unsigned short* gb[2];
  unsigned short* la[2];
  unsigned short* lb[2];
#pragma unroll
  for (int j = 0; j < 2; j++) {
    int c = j * 256 + tid;
    int r = c >> 2, cw = (c & 3) * 8;
    int gr = row0 + r; if (gr > M - 1) gr = M - 1;
    ga[j] = A + (size_t)gr * lda + cw;
    int gn = col0 + r; if (gn > Nc - 1) gn = Nc - 1;
    gb[j] = Bt + (size_t)gn * ldb + cw;
    la[j] = &As[(j * 256 + wave * 64) * 8];   // wave-uniform base
    lb[j] = &Bs[(j * 256 + wave * 64) * 8];
  }

  for (int k0 = 0; k0 < K; k0 += 32) {
#pragma unroll
    for (int j = 0; j < 2; j++) {
      gl2lds16(ga[j] + k0, la[j]);
      gl2lds16(gb[j] + k0, lb[j]);
    }
    __syncthreads();

    short8 af[4], bf[4];
#pragma unroll
    for (int i = 0; i < 4; i++) {
      af[i] = *reinterpret_cast<const short8*>(&As[(wr * 64 + i * 16 + mn) * 32 + q * 8]);
      bf[i] = *reinterpret_cast<const short8*>(&Bs[(wc * 64 + i * 16 + mn) * 32 + q * 8]);
    }
#pragma unroll
    for (int mi = 0; mi < 4; mi++)
#pragma unroll
      for (int ni = 0; ni < 4; ni++)
        acc[mi][ni] = __builtin_amdgcn_mfma_f32_16x16x32_bf16(af[mi], bf[ni], acc[mi][ni], 0, 0, 0);
    __syncthreads();
  }

#pragma unroll
  for (int mi = 0; mi < 4; mi++) {
#pragma unroll
    for (int ni = 0; ni < 4; ni++) {
      int gcol = col0 + wc * 64 + ni * 16 + mn;
      if (gcol >= Nc) continue;
      float b = bias ? bias[gcol] : 0.f;
#pragma unroll
      for (int r = 0; r < 4; r++) {
        int grow = row0 + wr * 64 + mi * 16 + q * 4 + r;
        if (grow >= M) continue;
        float v = acc[mi][ni][r] + b;
        if (Cb) {
          Cb[(size_t)grow * ldc + c0 + gcol] = f2bf(v);
        } else {
          float* p = Cf + (size_t)grow * ldc + c0 + gcol;
          if (accumulate) v += *p;
          *p = v;
        }
      }
    }
  }
}

// BN stats over bf16 matrix (strided)
__global__ void bn_stats_bf16_kernel(const unsigned short* __restrict__ h, int ld, int C,
                                     int N, float* __restrict__ sums) {
  int c = blockIdx.x * blockDim.x + threadIdx.x;
  if (c >= C) return;
  int r0 = blockIdx.y * 256;
  int r1 = min(N, r0 + 256);
  float s = 0.f, s2 = 0.f;
  for (int r = r0; r < r1; r++) {
    float v = bf2f(h[(size_t)r * ld + c]);
    s += v; s2 += v * v;
  }
  atomicAdd(&sums[c], s);
  atomicAdd(&sums[C + c], s2);
}

__global__ void scsh_kernel(const float* __restrict__ sums, const float* __restrict__ g,
                            const float* __restrict__ beta, float invN, int C,
                            float* __restrict__ scSh) {
  int c = blockIdx.x * blockDim.x + threadIdx.x;
  if (c >= C) return;
  float mu = sums[c] * invN;
  float var = sums[C + c] * invN - mu * mu;
  float s = rsqrtf(var + EPSB) * g[c];
  scSh[c] = s;
  scSh[C + c] = beta[c] - mu * s;
}

// BN apply (+optional relu) on bf16 matrix, 8 cols/thread
__global__ void bn_apply_bf16_kernel(unsigned short* __restrict__ h, int ld, int C8, int N,
                                     const float* __restrict__ scSh, int Cfull, int relu) {
  int idx = blockIdx.x * blockDim.x + threadIdx.x;
  if (idx >= N * C8) return;
  int row = idx / C8, c8 = idx - row * C8;
  unsigned short* p = h + (size_t)row * ld + c8 * 8;
  uint4 raw = *reinterpret_cast<uint4*>(p);
  float v[8];
  v[0] = bf2f((unsigned short)(raw.x & 0xffff)); v[1] = bf2f((unsigned short)(raw.x >> 16));
  v[2] = bf2f((unsigned short)(raw.y & 0xffff)); v[3] = bf2f((unsigned short)(raw.y >> 16));
  v[4] = bf2f((unsigned short)(raw.z & 0xffff)); v[5] = bf2f((unsigned short)(raw.z >> 16));
  v[6] = bf2f((unsigned short)(raw.w & 0xffff)); v[7] = bf2f((unsigned short)(raw.w >> 16));
#pragma unroll
  for (int j = 0; j < 8; j++) {
    int c = c8 * 8 + j;
    float o = v[j] * scSh[c] + scSh[Cfull + c];
    if (relu) o = fmaxf(o, 0.f);
    v[j] = o;
  }
  uint4 o;
  o.x = (unsigned int)f2bf(v[0]) | ((unsigned int)f2bf(v[1]) << 16);
  o.y = (unsigned int)f2bf(v[2]) | ((unsigned int)f2bf(v[3]) << 16);
  o.z = (unsigned int)f2bf(v[4]) | ((unsigned int)f2bf(v[5]) << 16);
  o.w = (unsigned int)f2bf(v[6]) | ((unsigned int)f2bf(v[7]) << 16);
  *reinterpret_cast<uint4*>(p) = o;
}

// fp32 BN pieces
__global__ void bn_stats_kernel(const float* __restrict__ h, int C, int N,
                                float* __restrict__ sums) {
  int c = blockIdx.x * blockDim.x + threadIdx.x;
  if (c >= C) return;
  int r0 = blockIdx.y * 256;
  int r1 = min(N, r0 + 256);
  float s = 0.f, s2 = 0.f;
  for (int r = r0; r < r1; r++) {
    float v = h[(size_t)r * C + c];
    s += v; s2 += v * v;
  }
  atomicAdd(&sums[c], s);
  atomicAdd(&sums[C + c], s2);
}

__global__ void bn_apply_kernel(float* __restrict__ h, int C, int N,
                                const float* __restrict__ sums, const float* __restrict__ g,
                                const float* __restrict__ beta, float invN, int relu) {
  int C4 = C >> 2;
  int c4 = blockIdx.x * blockDim.x + threadIdx.x;
  if (c4 >= C4) return;
  float sc[4], sh[4];
#pragma unroll
  for (int j = 0; j < 4; j++) {
    int c = c4 * 4 + j;
    float mu = sums[c] * invN;
    float var = sums[C + c] * invN - mu * mu;
    float s = rsqrtf(var + EPSB) * g[c];
    sc[j] = s; sh[j] = beta[c] - mu * s;
  }
  int r0 = blockIdx.y * 256, r1 = min(N, r0 + 256);
  for (int r = r0; r < r1; r++) {
    float4* p = reinterpret_cast<float4*>(h + (size_t)r * C) + c4;
    float4 v = *p;
    v.x = v.x * sc[0] + sh[0]; v.y = v.y * sc[1] + sh[1];
    v.z = v.z * sc[2] + sh[2]; v.w = v.w * sc[3] + sh[3];
    if (relu) {
      v.x = fmaxf(v.x, 0.f); v.y = fmaxf(v.y, 0.f);
      v.z = fmaxf(v.z, 0.f); v.w = fmaxf(v.w, 0.f);
    }
    *p = v;
  }
}

// ---------------- final: BN2-apply fused + linear + log_softmax ----------------

__global__ __launch_bounds__(256) void final_bn_kernel(const float* __restrict__ h2,
                                                       const float* __restrict__ scSh,
                                                       const float* __restrict__ Wl,
                                                       const float* __restrict__ bl,
                                                       float* __restrict__ out, int N) {
  __shared__ float Ws[3000];
  __shared__ float S[600];
  for (int i = threadIdx.x; i < 3000; i += 256) Ws[i] = Wl[i];
  for (int i = threadIdx.x; i < 600; i += 256) S[i] = scSh[i];
  __syncthreads();
  int r = blockIdx.x * blockDim.x + threadIdx.x;
  if (r >= N) return;
  float acc[10];
#pragma unroll
  for (int c = 0; c < 10; c++) acc[c] = bl[c];
  const float* hr = h2 + (size_t)r * 300;
  for (int k = 0; k < 300; k++) {
    float x = hr[k] * S[k] + S[300 + k];
#pragma unroll
    for (int c = 0; c < 10; c++) acc[c] += x * Ws[k * 10 + c];
  }
  float mx = acc[0];
#pragma unroll
  for (int c = 1; c < 10; c++) mx = fmaxf(mx, acc[c]);
  float se = 0.f;
#pragma unroll
  for (int c = 0; c < 10; c++) se += expf(acc[c] - mx);
  float lz = mx + logf(se);
#pragma unroll
  for (int c = 0; c < 10; c++) out[(size_t)r * 10 + c] = acc[c] - lz;
}

// plain final for Plan B
__global__ __launch_bounds__(256) void final_kernel(const float* __restrict__ h2,
                                                    const float* __restrict__ Wl,
                                                    const float* __restrict__ bl,
                                                    float* __restrict__ out, int N) {
  __shared__ float Ws[3000];
  for (int i = threadIdx.x; i < 3000; i += 256) Ws[i] = Wl[i];
  __syncthreads();
  int r = blockIdx.x * blockDim.x + threadIdx.x;
  if (r >= N) return;
  float acc[10];
#pragma unroll
  for (int c = 0; c < 10; c++) acc[c] = bl[c];
  const float* hr = h2 + (size_t)r * 300;
  for (int k = 0; k < 300; k++) {
    float x = hr[k];
#pragma unroll
    for (int c = 0; c < 10; c++) acc[c] += x * Ws[k * 10 + c];
  }
  float mx = acc[0];
#pragma unroll
  for (int c = 1; c < 10; c++) mx = fmaxf(mx, acc[c]);
  float se = 0.f;
#pragma unroll
  for (int c = 0; c < 10; c++) se += expf(acc[c] - mx);
  float lz = mx + logf(se);
#pragma unroll
  for (int c = 0; c < 10; c++) out[(size_t)r * 10 + c] = acc[c] - lz;
}

// ================= PLAN B (fp32 fallback, known-good) =================

__global__ void prop_kernel(const float* __restrict__ src, int srcLd4, int D4,
                            const int* __restrict__ off, const int2* __restrict__ ePack,
                            float* __restrict__ dst, int dstLd4,
                            const float* __restrict__ sub, int subLd4, float scale) {
  int v = blockIdx.x;
  int f4 = threadIdx.x;
  if (f4 >= D4) return;
  int s = off[v], e = off[v + 1];
  float ax = 0.f, ay = 0.f, az = 0.f, aw = 0.f;
  for (int i = s; i < e; i++) {
    int2 p = ePack[i];
    float w = __int_as_float(p.y);
    const float4 hv = *reinterpret_cast<const float4*>(src + ((size_t)p.x * srcLd4 + f4) * 4);
    ax += w * hv.x; ay += w * hv.y; az += w * hv.z; aw += w * hv.w;
  }
  float4 o;
  if (sub) {
    const float4 sv = *reinterpret_cast<const float4*>(sub + ((size_t)v * subLd4 + f4) * 4);
    o.x = scale * ax - sv.x; o.y = scale * ay - sv.y;
    o.z = scale * az - sv.z; o.w = scale * aw - sv.w;
  } else {
    o.x = ax; o.y = ay; o.z = az; o.w = aw;
  }
  *reinterpret_cast<float4*>(dst + ((size_t)v * dstLd4 + f4) * 4) = o;
}

#define BM 64
#define BN 64
#define BK 16

__global__ __launch_bounds__(256) void gemm_kernel(
    const float* __restrict__ A, int lda,
    const float* __restrict__ B, int ldb,
    float* __restrict__ C, int ldc, int c0,
    int M, int Nc, int K,
    const float* __restrict__ bias, int accumulate) {
  __shared__ float As[BK][BM + 4];
  __shared__ float Bs[BK][BN + 4];
  int tid = threadIdx.x;
  int tx = tid & 15, ty = tid >> 4;
  int row0 = blockIdx.y * BM, col0 = blockIdx.x * BN;
  float acc[4][4] = {};
  int aM = tid >> 2;
  int aK = (tid & 3) << 2;
  int bK = tid >> 4;
  int bN = (tid & 15) << 2;
  for (int k0 = 0; k0 < K; k0 += BK) {
    float4 av = make_float4(0.f, 0.f, 0.f, 0.f);
    int ar = row0 + aM;
    if (ar < M && k0 + aK < K)
      av = *reinterpret_cast<const float4*>(A + (size_t)ar * lda + k0 + aK);
    As[aK + 0][aM] = av.x; As[aK + 1][aM] = av.y;
    As[aK + 2][aM] = av.z; As[aK + 3][aM] = av.w;
    float4 bv = make_float4(0.f, 0.f, 0.f, 0.f);
    int bc = col0 + bN;
    if (bc < Nc && k0 + bK < K)
      bv = *reinterpret_cast<const float4*>(B + (size_t)(k0 + bK) * ldb + bc);
    Bs[bK][bN + 0] = bv.x; Bs[bK][bN + 1] = bv.y;
    Bs[bK][bN + 2] = bv.z; Bs[bK][bN + 3] = bv.w;
    __syncthreads();
#pragma unroll
    for (int k = 0; k < BK; k++) {
      float a0 = As[k][ty * 4 + 0], a1 = As[k][ty * 4 + 1];
      float a2 = As[k][ty * 4 + 2], a3 = As[k][ty * 4 + 3];
      float b0 = Bs[k][tx * 4 + 0], b1 = Bs[k][tx * 4 + 1];
      float b2 = Bs[k][tx * 4 + 2], b3 = Bs[k][tx * 4 + 3];
      acc[0][0] += a0 * b0; acc[0][1] += a0 * b1; acc[0][2] += a0 * b2; acc[0][3] += a0 * b3;
      acc[1][0] += a1 * b0; acc[1][1] += a1 * b1; acc[1][2] += a1 * b2; acc[1][3] += a1 * b3;
      acc[2][0] += a2 * b0; acc[2][1] += a2 * b1; acc[2][2] += a2 * b2; acc[2][3] += a2 * b3;
      acc[3][0] += a3 * b0; acc[3][1] += a3 * b1; acc[3][2] += a3 * b2; acc[3][3] += a3 * b3;
    }
    __syncthreads();
  }
#pragma unroll
  for (int i = 0; i < 4; i++) {
    int r = row0 + ty * 4 + i;
    if (r >= M) continue;
#pragma unroll
    for (int j = 0; j < 4; j++) {
      int c = col0 + tx * 4 + j;
      if (c >= Nc) continue;
      float v = acc[i][j];
      if (bias) v += bias[c];
      float* p = C + (size_t)r * ldc + c0 + c;
      if (accumulate) *p += v; else *p = v;
    }
  }
}

// ---------------- launch ----------------

static inline int gemm_grid(int M, int Nc) {
  int rowTiles = (M + 127) >> 7;
  int colTiles = (Nc + 127) >> 7;
  int rpx = (rowTiles + 7) >> 3;
  return 8 * rpx * colTiles;
}

extern "C" void kernel_launch(void* const* d_in, const int* in_sizes, int n_in,
                              void* d_out, int out_size, void* d_ws, size_t ws_size,
                              hipStream_t stream) {
  const float* x   = (const float*)d_in[0];
  const int*   ei  = (const int*)d_in[1];
  const float* ew  = (const float*)d_in[2];
  const float* W1a = (const float*)d_in[3];
  const float* b1a = (const float*)d_in[4];
  const float* W1b = (const float*)d_in[5];
  const float* b1b = (const float*)d_in[6];
  const float* W1c = (const float*)d_in[7];
  const float* b1c = (const float*)d_in[8];
  const float* g1  = (const float*)d_in[9];
  const float* be1 = (const float*)d_in[10];
  const float* W2a = (const float*)d_in[11];
  const float* b2a = (const float*)d_in[12];
  const float* W2b = (const float*)d_in[13];
  const float* b2b = (const float*)d_in[14];
  const float* W2c = (const float*)d_in[15];
  const float* b2c = (const float*)d_in[16];
  const float* g2  = (const float*)d_in[17];
  const float* be2 = (const float*)d_in[18];
  const float* Wl  = (const float*)d_in[19];
  const float* bl  = (const float*)d_in[20];
  float* out = (float*)d_out;

  const int N = in_sizes[0] / 512;
  const int E = in_sizes[1] / 2;
  const int* row = ei;
  const int* col = ei + E;
  (void)n_in; (void)out_size;

  int eb = (E + 255) / 256;
  int nb = (N + 255) / 256;
  int nb1 = (N + 1023) / 1024;

  // ---- common prefix layout ----
  char* ws = (char*)d_ws;
  size_t o = 0;
  int2*  ePack = (int2*)(ws + o);  o += (size_t)E * 8;
  float* dis   = (float*)(ws + o); o += (size_t)N * 4;
  int*   cnt   = (int*)(ws + o);   o += (size_t)N * 4;
  int*   off   = (int*)(ws + o);   o += (size_t)(N + 4) * 4;
  int*   wptr  = (int*)(ws + o);   o += (size_t)N * 4;
  int*   bsum  = (int*)(ws + o);   o += (size_t)(nb1 + 4) * 4;
  float* sums  = (float*)(ws + o); o += 2400 * 4;
  float* scSh  = (float*)(ws + o); o += 2400 * 4;
  float* bcat  = (float*)(ws + o); o += 304 * 4;
  o = (o + 255) & ~(size_t)255;
  size_t oCommon = o;

  // ---- plan A layout ----
  size_t oA = oCommon;
  unsigned short* Bt1a = (unsigned short*)(ws + oA); oA += (size_t)400 * 512 * 2;
  unsigned short* Bt1b = (unsigned short*)(ws + oA); oA += (size_t)400 * 1024 * 2;
  unsigned short* Bt1c = (unsigned short*)(ws + oA); oA += (size_t)400 * 1536 * 2;
  unsigned short* Bt2cat0 = (unsigned short*)(ws + oA); oA += (size_t)304 * 1216 * 2;
  unsigned short* Bt2z    = (unsigned short*)(ws + oA); oA += (size_t)304 * 1216 * 2;
  oA = (oA + 255) & ~(size_t)255;
  unsigned short* h1n = (unsigned short*)(ws + oA); oA += (size_t)N * 1216 * 2;
  oA = (oA + 255) & ~(size_t)255;
  float* h2f = (float*)(ws + oA); oA += (size_t)N * 300 * 4;
  oA = (oA + 255) & ~(size_t)255;
  // region X: Xcat (N x 1536 bf16) in phase 1; Zcat (N x 304) + U1 (N x 104) in phase 2
  unsigned short* Xcat = (unsigned short*)(ws + oA); oA += (size_t)N * 1536 * 2;
  unsigned short* Zcat = Xcat;
  unsigned short* U1 = Xcat + (size_t)N * 304;

  bool planA = (ws_size >= oA);

  // ---- graph prep (both plans) ----
  hipMemsetAsync(dis, 0, (size_t)N * 4, stream);
  hipMemsetAsync(cnt, 0, (size_t)N * 4, stream);
  degcnt_kernel<<<eb, 256, 0, stream>>>(row, col, ew, dis, cnt, E);
  dis_kernel<<<nb, 256, 0, stream>>>(dis, N);
  scan1_kernel<<<nb1, 1024, 0, stream>>>(cnt, off, bsum, N);
  scan2_kernel<<<1, 64, 0, stream>>>(bsum, off, nb1, N);
  scan3_kernel<<<nb, 256, 0, stream>>>(off, bsum, N);
  copy_kernel<<<nb, 256, 0, stream>>>(off, wptr, N);
  fill_kernel<<<eb, 256, 0, stream>>>(row, col, ew, dis, wptr, ePack, E);

  if (planA) {
    // weight prep + x cast
    wprep_kernel<<<(400 * 512 + 255) / 256, 256, 0, stream>>>(W1a, Bt1a, 512, 400, 512, 0);
    wprep_kernel<<<(400 * 1024 + 255) / 256, 256, 0, stream>>>(W1b, Bt1b, 1024, 400, 1024, 0);
    wprep_kernel<<<(400 * 1536 + 255) / 256, 256, 0, stream>>>(W1c, Bt1c, 1536, 400, 1536, 0);
    // layer-2 weights at ldb=1216 (K padded 1200->1216); memset keeps pad cols zero
    hipMemsetAsync(Bt2cat0, 0, (size_t)304 * 1216 * 2, stream);
    hipMemsetAsync(Bt2z, 0, (size_t)304 * 1216 * 2, stream);
    wprep_kernel<<<(100 * 1200 + 255) / 256, 256, 0, stream>>>(W2a, Bt2cat0, 1200, 100, 1216, 0);
    wprep_kernel<<<(100 * 1200 + 255) / 256, 256, 0, stream>>>(W2b, Bt2cat0, 1200, 100, 1216, 100);
    wprep_kernel<<<(100 * 1200 + 255) / 256, 256, 0, stream>>>(W2c, Bt2cat0, 1200, 100, 1216, 200);
    wprep_kernel<<<(100 * 1200 + 255) / 256, 256, 0, stream>>>(W2b + 1200 * 100, Bt2z, 1200, 100, 1216, 0);
    wprep_kernel<<<(100 * 1200 + 255) / 256, 256, 0, stream>>>(W2c + 1200 * 100, Bt2z, 1200, 100, 1216, 100);
    wprep_kernel<<<(100 * 1200 + 255) / 256, 256, 0, stream>>>(W2c + 2 * 1200 * 100, Bt2z, 1200, 100, 1216, 200);
    bcat_kernel<<<1, 320, 0, stream>>>(b2a, b2b, b2c, bcat);
    cast_x_kernel<<<(N * 128 + 255) / 256, 256, 0, stream>>>(x, Xcat, N);
    padzero_kernel<<<(N * 2 + 255) / 256, 256, 0, stream>>>(h1n, N);

    // layer-1 props (XCD-affine chunked): P1 = L x ; P2 = 2 L P1 - x
    int gridP = ((N + 7) / 8) * 8;
    prop_chunk_kernel<<<gridP, 256, 0, stream>>>(Xcat, 1536, 0, 512, -1,
                                                 off, ePack, 1.f, N);
    prop_chunk_kernel<<<gridP, 256, 0, stream>>>(Xcat, 1536, 512, 1024, 0,
                                                 off, ePack, 2.f, N);

    // layer-1 GEMMs -> h1n (bf16, ld 1216); XCD row-affine 1D grid
    int gA = gemm_grid(N, 400);
    gemm_bf16_kernel<<<gA, 256, 0, stream>>>(Xcat, 1536, Bt1a, 512, N, 400, 512,
                                             b1a, h1n, nullptr, 1216, 0, 0);
    gemm_bf16_kernel<<<gA, 256, 0, stream>>>(Xcat, 1536, Bt1b, 1024, N, 400, 1024,
                                             b1b, h1n, nullptr, 1216, 400, 0);
    gemm_bf16_kernel<<<gA, 256, 0, stream>>>(Xcat, 1536, Bt1c, 1536, N, 400, 1536,
                                             b1c, h1n, nullptr, 1216, 800, 0);

    // BN1 + ReLU on h1n
    hipMemsetAsync(sums, 0, 2400 * 4, stream);
    dim3 s1g((1200 + 255) / 256, (N + 255) / 256);
    bn_stats_bf16_kernel<<<s1g, 256, 0, stream>>>(h1n, 1216, 1200, N, sums);
    scsh_kernel<<<(1200 + 255) / 256, 256, 0, stream>>>(sums, g1, be1, 1.f / (float)N, 1200, scSh);
    bn_apply_bf16_kernel<<<((size_t)N * 150 + 255) / 256, 256, 0, stream>>>(
        h1n, 1216, 150, N, scSh, 1200, 1);

    // layer-2 GEMM 1: h2f = h1n*[W2a|W2b0|W2c0] + bias (fp32, 300 cols), K=1216
    int gB0 = gemm_grid(N, 300);
    gemm_bf16_kernel<<<gB0, 256, 0, stream>>>(h1n, 1216, Bt2cat0, 1216, N, 300, 1216,
                                              bcat, nullptr, h2f, 300, 0, 0);

    // layer-2 GEMM 2: Zcat = h1n*[W2b1|W2c1|W2c2|0] -> bf16 (304 cols), K=1216
    int gBz = gemm_grid(N, 304);
    gemm_bf16_kernel<<<gBz, 256, 0, stream>>>(h1n, 1216, Bt2z, 1216, N, 304, 1216,
                                              nullptr, Zcat, nullptr, 304, 0, 0);

    // commuted props
    prop_z_kernel<<<N, 64, 0, stream>>>(Zcat, off, ePack, h2f, U1);
    prop_u_kernel<<<N, 64, 0, stream>>>(U1, off, ePack, Zcat, h2f);

    // BN2 stats -> scSh; apply fused into final
    hipMemsetAsync(sums, 0, 2400 * 4, stream);
    dim3 s2g((300 + 255) / 256, (N + 255) / 256);
    bn_stats_kernel<<<s2g, 256, 0, stream>>>(h2f, 300, N, sums);
    scsh_kernel<<<(300 + 255) / 256, 256, 0, stream>>>(sums, g2, be2, 1.f / (float)N, 300, scSh);
    final_bn_kernel<<<nb, 256, 0, stream>>>(h2f, scSh, Wl, bl, out, N);
    return;
  }

  // ================= PLAN B (fp32 fallback) =================
  size_t oB = oCommon;
  float* h2 = (float*)(ws + oB); oB += (size_t)N * 300 * 4;
  oB = (oB + 255) & ~(size_t)255;
  float* h1 = (float*)(ws + oB); oB += (size_t)N * 1200 * 4;
  oB = (oB + 255) & ~(size_t)255;
  size_t avail = (ws_size > oB) ? (ws_size - oB) : 0;
  int C1 = 64;
  { const int opts[4] = {512, 256, 128, 64};
    for (int i = 0; i < 4; i++)
      if ((size_t)2 * N * opts[i] * 4 <= avail) { C1 = opts[i]; break; } }
  int C2 = 100;
  { const int opts[6] = {1200, 600, 400, 300, 200, 100};
    for (int i = 0; i < 6; i++)
      if ((size_t)2 * N * opts[i] * 4 <= avail) { C2 = opts[i]; break; } }
  int maxC = C1 > C2 ? C1 : C2;
  float* S1 = (float*)(ws + oB);
  float* S2 = S1 + (size_t)N * maxC;

  dim3 g1d((400 + BN - 1) / BN, (N + BM - 1) / BM);
  gemm_kernel<<<g1d, 256, 0, stream>>>(x, 512, W1a, 400, h1, 1200, 0,   N, 400, 512, b1a, 0);
  gemm_kernel<<<g1d, 256, 0, stream>>>(x, 512, W1b, 400, h1, 1200, 400, N, 400, 512, b1b, 0);
  gemm_kernel<<<g1d, 256, 0, stream>>>(x, 512, W1c, 400, h1, 1200, 800, N, 400, 512, b1c, 0);
  for (int c = 0; c < 512; c += C1) {
    int D4 = C1 / 4;
    int bt = ((D4 + 63) / 64) * 64;
    prop_kernel<<<N, bt, 0, stream>>>(x + c, 128, D4, off, ePack, S1, D4, nullptr, 0, 1.f);
    gemm_kernel<<<g1d, 256, 0, stream>>>(S1, C1, W1b + (size_t)(512 + c) * 400, 400, h1, 1200, 400, N, 400, C1, nullptr, 1);
    gemm_kernel<<<g1d, 256, 0, stream>>>(S1, C1, W1c + (size_t)(512 + c) * 400, 400, h1, 1200, 800, N, 400, C1, nullptr, 1);
    prop_kernel<<<N, bt, 0, stream>>>(S1, D4, D4, off, ePack, S2, D4, x + c, 128, 2.f);
    gemm_kernel<<<g1d, 256, 0, stream>>>(S2, C1, W1c + (size_t)(2 * 512 + c) * 400, 400, h1, 1200, 800, N, 400, C1, nullptr, 1);
  }

  hipMemsetAsync(sums, 0, 2400 * 4, stream);
  dim3 s1g((1200 + 255) / 256, (N + 255) / 256);
  bn_stats_kernel<<<s1g, 256, 0, stream>>>(h1, 1200, N, sums);
  dim3 a1g((300 + 63) / 64, (N + 255) / 256);
  bn_apply_kernel<<<a1g, 64, 0, stream>>>(h1, 1200, N, sums, g1, be1, 1.f / (float)N, 1);

  dim3 g2d((100 + BN - 1) / BN, (N + BM - 1) / BM);
  gemm_kernel<<<g2d, 256, 0, stream>>>(h1, 1200, W2a, 100, h2, 300, 0,   N, 100, 1200, b2a, 0);
  gemm_kernel<<<g2d, 256, 0, stream>>>(h1, 1200, W2b, 100, h2, 300, 100, N, 100, 1200, b2b, 0);
  gemm_kernel<<<g2d, 256, 0, stream>>>(h1, 1200, W2c, 100, h2, 300, 200, N, 100, 1200, b2c, 0);
  for (int c = 0; c < 1200; c += C2) {
    int D4 = C2 / 4;
    int bt = ((D4 + 63) / 64) * 64;
    prop_kernel<<<N, bt, 0, stream>>>(h1 + c, 300, D4, off, ePack, S1, D4, nullptr, 0, 1.f);
    gemm_kernel<<<g2d, 256, 0, stream>>>(S1, C2, W2b + (size_t)(1200 + c) * 100, 100, h2, 300, 100, N, 100, C2, nullptr, 1);
    gemm_kernel<<<g2d, 256, 0, stream>>>(S1, C2, W2c + (size_t)(1200 + c) * 100, 100, h2, 300, 200, N, 100, C2, nullptr, 1);
    prop_kernel<<<N, bt, 0, stream>>>(S1, D4, D4, off, ePack, S2, D4, h1 + c, 300, 2.f);
    gemm_kernel<<<g2d, 256, 0, stream>>>(S2, C2, W2c + (size_t)(2 * 1200 + c) * 100, 100, h2, 300, 200, N, 100, C2, nullptr, 1);
  }

  hipMemsetAsync(sums, 0, 2400 * 4, stream);
  dim3 s2g((300 + 255) / 256, (N + 255) / 256);
  bn_stats_kernel<<<s2g, 256, 0, stream>>>(h2, 300, N, sums);
  dim3 a2g((75 + 63) / 64, (N + 255) / 256);
  bn_apply_kernel<<<a2g, 64, 0, stream>>>(h2, 300, N, sums, g2, be2, 1.f / (float)N, 0);

  final_kernel<<<nb, 256, 0, stream>>>(h2, Wl, bl, out, N);
}

// Round 7
// 1685.904 us; speedup vs baseline: 1.6106x; 1.0622x over previous
//
#include <hip/hip_runtime.h>
#include <math.h>

#define EPSB 1e-5f

typedef __attribute__((ext_vector_type(8))) short short8;
typedef __attribute__((ext_vector_type(4))) float floatx4;
typedef __attribute__((ext_vector_type(2))) float floatx2;

__device__ inline float bf2f(unsigned short h) {
  union { unsigned int u; float f; } v; v.u = ((unsigned int)h) << 16; return v.f;
}
__device__ inline unsigned short f2bf(float f) {
  union { float f; unsigned int u; } v; v.f = f;
  unsigned int r = v.u + 0x7fffu + ((v.u >> 16) & 1u);  // RNE
  return (unsigned short)(r >> 16);
}

// async global->LDS 16B (wave-uniform LDS base + lane*16; global addr per-lane)
__device__ __forceinline__ void gl2lds16(const unsigned short* g, unsigned short* l) {
  __builtin_amdgcn_global_load_lds(
      (const __attribute__((address_space(1))) unsigned int*)g,
      (__attribute__((address_space(3))) unsigned int*)l, 16, 0, 0);
}

// packed bf16x8 accumulate: a[j] += {lo,hi}(g[j]) * wv  via v_pk_fma_f32
__device__ __forceinline__ void pk4(floatx2* a, uint4 g, floatx2 wv) {
  unsigned int u[4] = {g.x, g.y, g.z, g.w};
#pragma unroll
  for (int j = 0; j < 4; j++) {
    union { unsigned int q; float f; } lo, hi;
    lo.q = u[j] << 16;
    hi.q = u[j] & 0xffff0000u;
    floatx2 v; v[0] = lo.f; v[1] = hi.f;
    asm("v_pk_fma_f32 %0, %1, %2, %0" : "+v"(a[j]) : "v"(v), "v"(wv));
  }
}

// ---------------- graph prep ----------------

__global__ void degcnt_kernel(const int* __restrict__ row, const int* __restrict__ col,
                              const float* __restrict__ ew,
                              float* __restrict__ deg, int* __restrict__ cnt, int E) {
  int e = blockIdx.x * blockDim.x + threadIdx.x;
  if (e < E) {
    atomicAdd(&deg[row[e]], ew[e]);
    atomicAdd(&cnt[col[e]], 1);
  }
}

__global__ void dis_kernel(float* deg, int n) {
  int i = blockIdx.x * blockDim.x + threadIdx.x;
  if (i < n) { float d = deg[i]; deg[i] = d > 0.f ? rsqrtf(d) : 0.f; }
}

__global__ __launch_bounds__(1024) void scan1_kernel(const int* __restrict__ cnt,
                                                     int* __restrict__ off,
                                                     int* __restrict__ bsum, int n) {
  __shared__ int buf[1024];
  int tid = threadIdx.x;
  int idx = blockIdx.x * 1024 + tid;
  int v = (idx < n) ? cnt[idx] : 0;
  buf[tid] = v;
  __syncthreads();
  for (int s = 1; s < 1024; s <<= 1) {
    int t = (tid >= s) ? buf[tid - s] : 0;
    __syncthreads();
    if (tid >= s) buf[tid] += t;
    __syncthreads();
  }
  if (idx < n) off[idx] = buf[tid] - v;  // block-local exclusive
  if (tid == 1023) bsum[blockIdx.x] = buf[1023];
}

__global__ void scan2_kernel(int* __restrict__ bsum, int* __restrict__ off,
                             int nb, int n) {
  if (threadIdx.x == 0 && blockIdx.x == 0) {
    int run = 0;
    for (int k = 0; k < nb; k++) { int t = bsum[k]; bsum[k] = run; run += t; }
    off[n] = run;
  }
}

__global__ void scan3_kernel(int* __restrict__ off, const int* __restrict__ bsum, int n) {
  int i = blockIdx.x * blockDim.x + threadIdx.x;
  if (i < n) off[i] += bsum[i >> 10];
}

__global__ void copy_kernel(const int* __restrict__ src, int* __restrict__ dst, int n) {
  int i = blockIdx.x * blockDim.x + threadIdx.x;
  if (i < n) dst[i] = src[i];
}

// packed edge record: .x = source row index, .y = float bits of norm weight
__global__ void fill_kernel(const int* __restrict__ row, const int* __restrict__ col,
                            const float* __restrict__ ew, const float* __restrict__ dis,
                            int* __restrict__ wptr, int2* __restrict__ ePack, int E) {
  int e = blockIdx.x * blockDim.x + threadIdx.x;
  if (e < E) {
    int r = row[e], c = col[e];
    int p = atomicAdd(&wptr[c], 1);
    float nv = -dis[r] * ew[e] * dis[c];
    ePack[p] = make_int2(r, __float_as_int(nv));
  }
}

// ================= PLAN A (bf16 + MFMA) =================

// cast x (N x 512 fp32) into Xcat cols [0,512) (ld 1536, bf16)
__global__ void cast_x_kernel(const float* __restrict__ x, unsigned short* __restrict__ xb,
                              int N) {
  int idx = blockIdx.x * blockDim.x + threadIdx.x;
  if (idx >= N * 128) return;
  int row = idx >> 7, c4 = idx & 127;
  float4 v = *reinterpret_cast<const float4*>(x + (size_t)row * 512 + c4 * 4);
  union { unsigned int u[2]; } p;
  p.u[0] = (unsigned int)f2bf(v.x) | ((unsigned int)f2bf(v.y) << 16);
  p.u[1] = (unsigned int)f2bf(v.z) | ((unsigned int)f2bf(v.w) << 16);
  *reinterpret_cast<uint2*>(xb + (size_t)row * 1536 + c4 * 4) = make_uint2(p.u[0], p.u[1]);
}

// transpose+cast weights: W[k][n] fp32 (n fastest) -> Bt[rowOff+n][k] bf16 (ld ldBt)
__global__ void wprep_kernel(const float* __restrict__ W, unsigned short* __restrict__ Bt,
                             int Ktot, int Nout, int ldBt, int rowOff) {
  int idx = blockIdx.x * blockDim.x + threadIdx.x;
  if (idx >= Ktot * Nout) return;
  int k = idx / Nout, n = idx - k * Nout;
  Bt[(size_t)(rowOff + n) * ldBt + k] = f2bf(W[idx]);
}

// zero pad cols [1200,1216) of h1n (ld 1216)
__global__ void padzero_kernel(unsigned short* __restrict__ h, int N) {
  int i = blockIdx.x * blockDim.x + threadIdx.x;
  if (i >= N * 2) return;
  *reinterpret_cast<uint4*>(h + (size_t)(i >> 1) * 1216 + 1200 + (i & 1) * 8) =
      make_uint4(0, 0, 0, 0);
}

// concat 3 segments of length seg into dst
__global__ void bcat_kernel(const float* __restrict__ a, const float* __restrict__ b,
                            const float* __restrict__ c, float* __restrict__ dst, int seg) {
  int i = blockIdx.x * blockDim.x + threadIdx.x;
  if (i >= 3 * seg) return;
  float v;
  if (i < seg) v = a[i];
  else if (i < 2 * seg) v = b[i - seg];
  else v = c[i - 2 * seg];
  dst[i] = v;
}

// ---- XCD-affine chunked layer-1 prop (benched floor: 177 us — do not touch) ----
__global__ __launch_bounds__(256) void prop_chunk_kernel(
    unsigned short* __restrict__ base, int ld,
    int srcCol, int dstCol, int subCol,    // subCol < 0 => no sub
    const int* __restrict__ off, const int2* __restrict__ ePack,
    float scale, int N) {
  int chunk = blockIdx.x & 7;
  int g = blockIdx.x >> 3;
  int tid = threadIdx.x;
  int slot = (tid >> 3) & 3;
  int c8 = tid & 7;
  int v = g * 8 + (tid >> 5);
  bool valid = v < N;
  int vv = valid ? v : N - 1;
  int co = chunk * 64 + c8 * 8;
  const unsigned short* src = base + srcCol + co;
  int s = off[vv], e = off[vv + 1];
  int len = e - s;
  int s0 = s + (len * slot >> 2);
  int e0 = s + (len * (slot + 1) >> 2);
  floatx2 a2[4] = {}, b2[4] = {};
  int i = s0;
  for (; i + 3 < e0; i += 4) {
    int2 p0 = ePack[i];
    int2 p1 = ePack[i + 1];
    int2 p2 = ePack[i + 2];
    int2 p3 = ePack[i + 3];
    uint4 g0 = *reinterpret_cast<const uint4*>(src + (size_t)p0.x * ld);
    uint4 g1 = *reinterpret_cast<const uint4*>(src + (size_t)p1.x * ld);
    uint4 g2 = *reinterpret_cast<const uint4*>(src + (size_t)p2.x * ld);
    uint4 g3 = *reinterpret_cast<const uint4*>(src + (size_t)p3.x * ld);
    floatx2 w0; w0[0] = w0[1] = __int_as_float(p0.y);
    floatx2 w1; w1[0] = w1[1] = __int_as_float(p1.y);
    floatx2 w2; w2[0] = w2[1] = __int_as_float(p2.y);
    floatx2 w3; w3[0] = w3[1] = __int_as_float(p3.y);
    pk4(a2, g0, w0);
    pk4(b2, g1, w1);
    pk4(a2, g2, w2);
    pk4(b2, g3, w3);
  }
  for (; i < e0; i++) {
    int2 p = ePack[i];
    uint4 gg = *reinterpret_cast<const uint4*>(src + (size_t)p.x * ld);
    floatx2 wv; wv[0] = wv[1] = __int_as_float(p.y);
    pk4(a2, gg, wv);
  }
  float a[8];
#pragma unroll
  for (int j = 0; j < 4; j++) {
    a[2 * j]     = a2[j][0] + b2[j][0];
    a[2 * j + 1] = a2[j][1] + b2[j][1];
  }
#pragma unroll
  for (int j = 0; j < 8; j++) {
    a[j] += __shfl_xor(a[j], 8);
    a[j] += __shfl_xor(a[j], 16);
  }
  if (slot != 0 || !valid) return;
  if (subCol >= 0) {
    uint4 sv = *reinterpret_cast<const uint4*>(base + subCol + co + (size_t)v * ld);
    a[0] = scale * a[0] - bf2f((unsigned short)(sv.x & 0xffff));
    a[1] = scale * a[1] - bf2f((unsigned short)(sv.x >> 16));
    a[2] = scale * a[2] - bf2f((unsigned short)(sv.y & 0xffff));
    a[3] = scale * a[3] - bf2f((unsigned short)(sv.y >> 16));
    a[4] = scale * a[4] - bf2f((unsigned short)(sv.z & 0xffff));
    a[5] = scale * a[5] - bf2f((unsigned short)(sv.z >> 16));
    a[6] = scale * a[6] - bf2f((unsigned short)(sv.w & 0xffff));
    a[7] = scale * a[7] - bf2f((unsigned short)(sv.w >> 16));
  }
  uint4 o;
  o.x = (unsigned int)f2bf(a[0]) | ((unsigned int)f2bf(a[1]) << 16);
  o.y = (unsigned int)f2bf(a[2]) | ((unsigned int)f2bf(a[3]) << 16);
  o.z = (unsigned int)f2bf(a[4]) | ((unsigned int)f2bf(a[5]) << 16);
  o.w = (unsigned int)f2bf(a[6]) | ((unsigned int)f2bf(a[7]) << 16);
  *reinterpret_cast<uint4*>(base + dstCol + co + (size_t)v * ld) = o;
}

// ---- commuted layer-2 props ----
__global__ void prop_z_kernel(const unsigned short* __restrict__ Zcat,
                              const int* __restrict__ off, const int2* __restrict__ ePack,
                              float* __restrict__ h2f, unsigned short* __restrict__ U1) {
  int v = blockIdx.x;
  int f8 = threadIdx.x;
  if (f8 >= 38) return;
  int s = off[v], e = off[v + 1];
  floatx2 a2[4] = {}, b2[4] = {};
  int i = s;
  for (; i + 3 < e; i += 4) {
    int2 p0 = ePack[i];
    int2 p1 = ePack[i + 1];
    int2 p2 = ePack[i + 2];
    int2 p3 = ePack[i + 3];
    uint4 g0 = *reinterpret_cast<const uint4*>(Zcat + (size_t)p0.x * 304 + f8 * 8);
    uint4 g1 = *reinterpret_cast<const uint4*>(Zcat + (size_t)p1.x * 304 + f8 * 8);
    uint4 g2 = *reinterpret_cast<const uint4*>(Zcat + (size_t)p2.x * 304 + f8 * 8);
    uint4 g3 = *reinterpret_cast<const uint4*>(Zcat + (size_t)p3.x * 304 + f8 * 8);
    floatx2 w0; w0[0] = w0[1] = __int_as_float(p0.y);
    floatx2 w1; w1[0] = w1[1] = __int_as_float(p1.y);
    floatx2 w2; w2[0] = w2[1] = __int_as_float(p2.y);
    floatx2 w3; w3[0] = w3[1] = __int_as_float(p3.y);
    pk4(a2, g0, w0);
    pk4(b2, g1, w1);
    pk4(a2, g2, w2);
    pk4(b2, g3, w3);
  }
  for (; i < e; i++) {
    int2 p = ePack[i];
    uint4 raw = *reinterpret_cast<const uint4*>(Zcat + (size_t)p.x * 304 + f8 * 8);
    floatx2 wv; wv[0] = wv[1] = __int_as_float(p.y);
    pk4(a2, raw, wv);
  }
  float a[8];
#pragma unroll
  for (int j = 0; j < 4; j++) {
    a[2 * j]     = a2[j][0] + b2[j][0];
    a[2 * j + 1] = a2[j][1] + b2[j][1];
  }
  if (f8 < 25) {
    float* p = h2f + (size_t)v * 300 + 100 + f8 * 8;
#pragma unroll
    for (int j = 0; j < 8; j++) p[j] += a[j];
  } else {
    uint4 o;
    o.x = (unsigned int)f2bf(a[0]) | ((unsigned int)f2bf(a[1]) << 16);
    o.y = (unsigned int)f2bf(a[2]) | ((unsigned int)f2bf(a[3]) << 16);
    o.z = (unsigned int)f2bf(a[4]) | ((unsigned int)f2bf(a[5]) << 16);
    o.w = (unsigned int)f2bf(a[6]) | ((unsigned int)f2bf(a[7]) << 16);
    *reinterpret_cast<uint4*>(U1 + (size_t)v * 104 + (f8 - 25) * 8) = o;
  }
}

__global__ void prop_u_kernel(const unsigned short* __restrict__ U1,
                              const int* __restrict__ off, const int2* __restrict__ ePack,
                              const unsigned short* __restrict__ Zcat,
                              float* __restrict__ h2f) {
  int v = blockIdx.x;
  int f8 = threadIdx.x;
  if (f8 >= 13) return;
  int s = off[v], e = off[v + 1];
  floatx2 a2[4] = {}, b2[4] = {};
  int i = s;
  for (; i + 3 < e; i += 4) {
    int2 p0 = ePack[i];
    int2 p1 = ePack[i + 1];
    int2 p2 = ePack[i + 2];
    int2 p3 = ePack[i + 3];
    uint4 g0 = *reinterpret_cast<const uint4*>(U1 + (size_t)p0.x * 104 + f8 * 8);
    uint4 g1 = *reinterpret_cast<const uint4*>(U1 + (size_t)p1.x * 104 + f8 * 8);
    uint4 g2 = *reinterpret_cast<const uint4*>(U1 + (size_t)p2.x * 104 + f8 * 8);
    uint4 g3 = *reinterpret_cast<const uint4*>(U1 + (size_t)p3.x * 104 + f8 * 8);
    floatx2 w0; w0[0] = w0[1] = __int_as_float(p0.y);
    floatx2 w1; w1[0] = w1[1] = __int_as_float(p1.y);
    floatx2 w2; w2[0] = w2[1] = __int_as_float(p2.y);
    floatx2 w3; w3[0] = w3[1] = __int_as_float(p3.y);
    pk4(a2, g0, w0);
    pk4(b2, g1, w1);
    pk4(a2, g2, w2);
    pk4(b2, g3, w3);
  }
  for (; i < e; i++) {
    int2 p = ePack[i];
    uint4 raw = *reinterpret_cast<const uint4*>(U1 + (size_t)p.x * 104 + f8 * 8);
    floatx2 wv; wv[0] = wv[1] = __int_as_float(p.y);
    pk4(a2, raw, wv);
  }
  float a[8];
#pragma unroll
  for (int j = 0; j < 4; j++) {
    a[2 * j]     = a2[j][0] + b2[j][0];
    a[2 * j + 1] = a2[j][1] + b2[j][1];
  }
  const unsigned short* z2 = Zcat + (size_t)v * 304 + 200;
  float* p = h2f + (size_t)v * 300 + 200;
#pragma unroll
  for (int j = 0; j < 8; j++) {
    int c = f8 * 8 + j;
    if (c < 100) p[c] += 2.f * a[j] - bf2f(z2[c]);
  }
}

// ---- bf16 MFMA GEMM, m97 structure + XCD row-affine remap ----
// l1mode: per-col-tile K (block-structured B: cols<400 K=512, <800 K=1024, else Kfull).
// dual:   gcol<300 -> Cf fp32 (ld 300, +bias); 304<=gcol<Nc -> Cb bf16 (ld 304).
__global__ __launch_bounds__(256) void gemm_bf16_kernel(
    const unsigned short* __restrict__ A, int lda,
    const unsigned short* __restrict__ Bt, int ldb,
    int M, int Nc, int K,
    const float* __restrict__ bias,
    unsigned short* __restrict__ Cb, float* __restrict__ Cf, int ldc, int c0,
    int accumulate, int l1mode, int dual) {
  __shared__ __align__(16) unsigned short As[128 * 32];
  __shared__ __align__(16) unsigned short Bs[128 * 32];
  int colTiles = (Nc + 127) >> 7;
  int rowTiles = (M + 127) >> 7;
  int L = blockIdx.x;
  int xcd = L & 7, slot = L >> 3;
  int rpx = (rowTiles + 7) >> 3;
  int rloc = slot / colTiles;
  int ct = slot - rloc * colTiles;
  int rt = xcd * rpx + rloc;
  if (rt >= rowTiles) return;
  int row0 = rt << 7, col0 = ct << 7;

  int Kt = K;
  if (l1mode) Kt = (col0 + 127 < 400) ? 512 : ((col0 + 127 < 800) ? 1024 : K);

  int tid = threadIdx.x;
  int wave = tid >> 6, lane = tid & 63;
  int q = lane >> 4, mn = lane & 15;
  int wr = wave >> 1, wc = wave & 1;
  floatx4 acc[4][4] = {};

  const unsigned short* ga[2];
  const unsigned short* gb[2];
  unsigned short* la[2];
  unsigned short* lb[2];
#pragma unroll
  for (int j = 0; j < 2; j++) {
    int c = j * 256 + tid;
    int r = c >> 2, cw = (c & 3) * 8;
    int gr = row0 + r; if (gr > M - 1) gr = M - 1;
    ga[j] = A + (size_t)gr * lda + cw;
    int gn = col0 + r; if (gn > Nc - 1) gn = Nc - 1;
    gb[j] = Bt + (size_t)gn * ldb + cw;
    la[j] = &As[(j * 256 + wave * 64) * 8];   // wave-uniform base
    lb[j] = &Bs[(j * 256 + wave * 64) * 8];
  }

  for (int k0 = 0; k0 < Kt; k0 += 32) {
#pragma unroll
    for (int j = 0; j < 2; j++) {
      gl2lds16(ga[j] + k0, la[j]);
      gl2lds16(gb[j] + k0, lb[j]);
    }
    __syncthreads();

    short8 af[4], bf[4];
#pragma unroll
    for (int i = 0; i < 4; i++) {
      af[i] = *reinterpret_cast<const short8*>(&As[(wr * 64 + i * 16 + mn) * 32 + q * 8]);
      bf[i] = *reinterpret_cast<const short8*>(&Bs[(wc * 64 + i * 16 + mn) * 32 + q * 8]);
    }
#pragma unroll
    for (int mi = 0; mi < 4; mi++)
#pragma unroll
      for (int ni = 0; ni < 4; ni++)
        acc[mi][ni] = __builtin_amdgcn_mfma_f32_16x16x32_bf16(af[mi], bf[ni], acc[mi][ni], 0, 0, 0);
    __syncthreads();
  }

#pragma unroll
  for (int mi = 0; mi < 4; mi++) {
#pragma unroll
    for (int ni = 0; ni < 4; ni++) {
      int gcol = col0 + wc * 64 + ni * 16 + mn;
      if (gcol >= Nc) continue;
      if (dual) {
        if (gcol < 300) {
          float b = bias[gcol];
#pragma unroll
          for (int r = 0; r < 4; r++) {
            int grow = row0 + wr * 64 + mi * 16 + q * 4 + r;
            if (grow >= M) continue;
            Cf[(size_t)grow * 300 + gcol] = acc[mi][ni][r] + b;
          }
        } else if (gcol >= 304) {
#pragma unroll
          for (int r = 0; r < 4; r++) {
            int grow = row0 + wr * 64 + mi * 16 + q * 4 + r;
            if (grow >= M) continue;
            Cb[(size_t)grow * 304 + (gcol - 304)] = f2bf(acc[mi][ni][r]);
          }
        }
      } else {
        float b = bias ? bias[gcol] : 0.f;
#pragma unroll
        for (int r = 0; r < 4; r++) {
          int grow = row0 + wr * 64 + mi * 16 + q * 4 + r;
          if (grow >= M) continue;
          float v = acc[mi][ni][r] + b;
          if (Cb) {
            Cb[(size_t)grow * ldc + c0 + gcol] = f2bf(v);
          } else {
            float* p = Cf + (size_t)grow * ldc + c0 + gcol;
            if (accumulate) v += *p;
            *p = v;
          }
        }
      }
    }
  }
}

// BN stats over bf16 matrix (strided)
__global__ void bn_stats_bf16_kernel(const unsigned short* __restrict__ h, int ld, int C,
                                     int N, float* __restrict__ sums) {
  int c = blockIdx.x * blockDim.x + threadIdx.x;
  if (c >= C) return;
  int r0 = blockIdx.y * 256;
  int r1 = min(N, r0 + 256);
  float s = 0.f, s2 = 0.f;
  for (int r = r0; r < r1; r++) {
    float v = bf2f(h[(size_t)r * ld + c]);
    s += v; s2 += v * v;
  }
  atomicAdd(&sums[c], s);
  atomicAdd(&sums[C + c], s2);
}

__global__ void scsh_kernel(const float* __restrict__ sums, const float* __restrict__ g,
                            const float* __restrict__ beta, float invN, int C,
                            float* __restrict__ scSh) {
  int c = blockIdx.x * blockDim.x + threadIdx.x;
  if (c >= C) return;
  float mu = sums[c] * invN;
  float var = sums[C + c] * invN - mu * mu;
  float s = rsqrtf(var + EPSB) * g[c];
  scSh[c] = s;
  scSh[C + c] = beta[c] - mu * s;
}

// BN apply (+optional relu) on bf16 matrix, 8 cols/thread
__global__ void bn_apply_bf16_kernel(unsigned short* __restrict__ h, int ld, int C8, int N,
                                     const float* __restrict__ scSh, int Cfull, int relu) {
  int idx = blockIdx.x * blockDim.x + threadIdx.x;
  if (idx >= N * C8) return;
  int row = idx / C8, c8 = idx - row * C8;
  unsigned short* p = h + (size_t)row * ld + c8 * 8;
  uint4 raw = *reinterpret_cast<uint4*>(p);
  float v[8];
  v[0] = bf2f((unsigned short)(raw.x & 0xffff)); v[1] = bf2f((unsigned short)(raw.x >> 16));
  v[2] = bf2f((unsigned short)(raw.y & 0xffff)); v[3] = bf2f((unsigned short)(raw.y >> 16));
  v[4] = bf2f((unsigned short)(raw.z & 0xffff)); v[5] = bf2f((unsigned short)(raw.z >> 16));
  v[6] = bf2f((unsigned short)(raw.w & 0xffff)); v[7] = bf2f((unsigned short)(raw.w >> 16));
#pragma unroll
  for (int j = 0; j < 8; j++) {
    int c = c8 * 8 + j;
    float o = v[j] * scSh[c] + scSh[Cfull + c];
    if (relu) o = fmaxf(o, 0.f);
    v[j] = o;
  }
  uint4 o;
  o.x = (unsigned int)f2bf(v[0]) | ((unsigned int)f2bf(v[1]) << 16);
  o.y = (unsigned int)f2bf(v[2]) | ((unsigned int)f2bf(v[3]) << 16);
  o.z = (unsigned int)f2bf(v[4]) | ((unsigned int)f2bf(v[5]) << 16);
  o.w = (unsigned int)f2bf(v[6]) | ((unsigned int)f2bf(v[7]) << 16);
  *reinterpret_cast<uint4*>(p) = o;
}

// fp32 BN pieces
__global__ void bn_stats_kernel(const float* __restrict__ h, int C, int N,
                                float* __restrict__ sums) {
  int c = blockIdx.x * blockDim.x + threadIdx.x;
  if (c >= C) return;
  int r0 = blockIdx.y * 256;
  int r1 = min(N, r0 + 256);
  float s = 0.f, s2 = 0.f;
  for (int r = r0; r < r1; r++) {
    float v = h[(size_t)r * C + c];
    s += v; s2 += v * v;
  }
  atomicAdd(&sums[c], s);
  atomicAdd(&sums[C + c], s2);
}

__global__ void bn_apply_kernel(float* __restrict__ h, int C, int N,
                                const float* __restrict__ sums, const float* __restrict__ g,
                                const float* __restrict__ beta, float invN, int relu) {
  int C4 = C >> 2;
  int c4 = blockIdx.x * blockDim.x + threadIdx.x;
  if (c4 >= C4) return;
  float sc[4], sh[4];
#pragma unroll
  for (int j = 0; j < 4; j++) {
    int c = c4 * 4 + j;
    float mu = sums[c] * invN;
    float var = sums[C + c] * invN - mu * mu;
    float s = rsqrtf(var + EPSB) * g[c];
    sc[j] = s; sh[j] = beta[c] - mu * s;
  }
  int r0 = blockIdx.y * 256, r1 = min(N, r0 + 256);
  for (int r = r0; r < r1; r++) {
    float4* p = reinterpret_cast<float4*>(h + (size_t)r * C) + c4;
    float4 v = *p;
    v.x = v.x * sc[0] + sh[0]; v.y = v.y * sc[1] + sh[1];
    v.z = v.z * sc[2] + sh[2]; v.w = v.w * sc[3] + sh[3];
    if (relu) {
      v.x = fmaxf(v.x, 0.f); v.y = fmaxf(v.y, 0.f);
      v.z = fmaxf(v.z, 0.f); v.w = fmaxf(v.w, 0.f);
    }
    *p = v;
  }
}

// ---------------- final: BN2-apply fused + linear + log_softmax ----------------

__global__ __launch_bounds__(256) void final_bn_kernel(const float* __restrict__ h2,
                                                       const float* __restrict__ scSh,
                                                       const float* __restrict__ Wl,
                                                       const float* __restrict__ bl,
                                                       float* __restrict__ out, int N) {
  __shared__ float Ws[3000];
  __shared__ float S[600];
  for (int i = threadIdx.x; i < 3000; i += 256) Ws[i] = Wl[i];
  for (int i = threadIdx.x; i < 600; i += 256) S[i] = scSh[i];
  __syncthreads();
  int r = blockIdx.x * blockDim.x + threadIdx.x;
  if (r >= N) return;
  float acc[10];
#pragma unroll
  for (int c = 0; c < 10; c++) acc[c] = bl[c];
  const float* hr = h2 + (size_t)r * 300;
  for (int k = 0; k < 300; k++) {
    float x = hr[k] * S[k] + S[300 + k];
#pragma unroll
    for (int c = 0; c < 10; c++) acc[c] += x * Ws[k * 10 + c];
  }
  float mx = acc[0];
#pragma unroll
  for (int c = 1; c < 10; c++) mx = fmaxf(mx, acc[c]);
  float se = 0.f;
#pragma unroll
  for (int c = 0; c < 10; c++) se += expf(acc[c] - mx);
  float lz = mx + logf(se);
#pragma unroll
  for (int c = 0; c < 10; c++) out[(size_t)r * 10 + c] = acc[c] - lz;
}

// plain final for Plan B
__global__ __launch_bounds__(256) void final_kernel(const float* __restrict__ h2,
                                                    const float* __restrict__ Wl,
                                                    const float* __restrict__ bl,
                                                    float* __restrict__ out, int N) {
  __shared__ float Ws[3000];
  for (int i = threadIdx.x; i < 3000; i += 256) Ws[i] = Wl[i];
  __syncthreads();
  int r = blockIdx.x * blockDim.x + threadIdx.x;
  if (r >= N) return;
  float acc[10];
#pragma unroll
  for (int c = 0; c < 10; c++) acc[c] = bl[c];
  const float* hr = h2 + (size_t)r * 300;
  for (int k = 0; k < 300; k++) {
    float x = hr[k];
#pragma unroll
    for (int c = 0; c < 10; c++) acc[c] += x * Ws[k * 10 + c];
  }
  float mx = acc[0];
#pragma unroll
  for (int c = 1; c < 10; c++) mx = fmaxf(mx, acc[c]);
  float se = 0.f;
#pragma unroll
  for (int c = 0; c < 10; c++) se += expf(acc[c] - mx);
  float lz = mx + logf(se);
#pragma unroll
  for (int c = 0; c < 10; c++) out[(size_t)r * 10 + c] = acc[c] - lz;
}

// ================= PLAN B (fp32 fallback, known-good) =================

__global__ void prop_kernel(const float* __restrict__ src, int srcLd4, int D4,
                            const int* __restrict__ off, const int2* __restrict__ ePack,
                            float* __restrict__ dst, int dstLd4,
                            const float* __restrict__ sub, int subLd4, float scale) {
  int v = blockIdx.x;
  int f4 = threadIdx.x;
  if (f4 >= D4) return;
  int s = off[v], e = off[v + 1];
  float ax = 0.f, ay = 0.f, az = 0.f, aw = 0.f;
  for (int i = s; i < e; i++) {
    int2 p = ePack[i];
    float w = __int_as_float(p.y);
    const float4 hv = *reinterpret_cast<const float4*>(src + ((size_t)p.x * srcLd4 + f4) * 4);
    ax += w * hv.x; ay += w * hv.y; az += w * hv.z; aw += w * hv.w;
  }
  float4 o;
  if (sub) {
    const float4 sv = *reinterpret_cast<const float4*>(sub + ((size_t)v * subLd4 + f4) * 4);
    o.x = scale * ax - sv.x; o.y = scale * ay - sv.y;
    o.z = scale * az - sv.z; o.w = scale * aw - sv.w;
  } else {
    o.x = ax; o.y = ay; o.z = az; o.w = aw;
  }
  *reinterpret_cast<float4*>(dst + ((size_t)v * dstLd4 + f4) * 4) = o;
}

#define BM 64
#define BN 64
#define BK 16

__global__ __launch_bounds__(256) void gemm_kernel(
    const float* __restrict__ A, int lda,
    const float* __restrict__ B, int ldb,
    float* __restrict__ C, int ldc, int c0,
    int M, int Nc, int K,
    const float* __restrict__ bias, int accumulate) {
  __shared__ float As[BK][BM + 4];
  __shared__ float Bs[BK][BN + 4];
  int tid = threadIdx.x;
  int tx = tid & 15, ty = tid >> 4;
  int row0 = blockIdx.y * BM, col0 = blockIdx.x * BN;
  float acc[4][4] = {};
  int aM = tid >> 2;
  int aK = (tid & 3) << 2;
  int bK = tid >> 4;
  int bN = (tid & 15) << 2;
  for (int k0 = 0; k0 < K; k0 += BK) {
    float4 av = make_float4(0.f, 0.f, 0.f, 0.f);
    int ar = row0 + aM;
    if (ar < M && k0 + aK < K)
      av = *reinterpret_cast<const float4*>(A + (size_t)ar * lda + k0 + aK);
    As[aK + 0][aM] = av.x; As[aK + 1][aM] = av.y;
    As[aK + 2][aM] = av.z; As[aK + 3][aM] = av.w;
    float4 bv = make_float4(0.f, 0.f, 0.f, 0.f);
    int bc = col0 + bN;
    if (bc < Nc && k0 + bK < K)
      bv = *reinterpret_cast<const float4*>(B + (size_t)(k0 + bK) * ldb + bc);
    Bs[bK][bN + 0] = bv.x; Bs[bK][bN + 1] = bv.y;
    Bs[bK][bN + 2] = bv.z; Bs[bK][bN + 3] = bv.w;
    __syncthreads();
#pragma unroll
    for (int k = 0; k < BK; k++) {
      float a0 = As[k][ty * 4 + 0], a1 = As[k][ty * 4 + 1];
      float a2 = As[k][ty * 4 + 2], a3 = As[k][ty * 4 + 3];
      float b0 = Bs[k][tx * 4 + 0], b1 = Bs[k][tx * 4 + 1];
      float b2 = Bs[k][tx * 4 + 2], b3 = Bs[k][tx * 4 + 3];
      acc[0][0] += a0 * b0; acc[0][1] += a0 * b1; acc[0][2] += a0 * b2; acc[0][3] += a0 * b3;
      acc[1][0] += a1 * b0; acc[1][1] += a1 * b1; acc[1][2] += a1 * b2; acc[1][3] += a1 * b3;
      acc[2][0] += a2 * b0; acc[2][1] += a2 * b1; acc[2][2] += a2 * b2; acc[2][3] += a2 * b3;
      acc[3][0] += a3 * b0; acc[3][1] += a3 * b1; acc[3][2] += a3 * b2; acc[3][3] += a3 * b3;
    }
    __syncthreads();
  }
#pragma unroll
  for (int i = 0; i < 4; i++) {
    int r = row0 + ty * 4 + i;
    if (r >= M) continue;
#pragma unroll
    for (int j = 0; j < 4; j++) {
      int c = col0 + tx * 4 + j;
      if (c >= Nc) continue;
      float v = acc[i][j];
      if (bias) v += bias[c];
      float* p = C + (size_t)r * ldc + c0 + c;
      if (accumulate) *p += v; else *p = v;
    }
  }
}

// ---------------- launch ----------------

static inline int gemm_grid(int M, int Nc) {
  int rowTiles = (M + 127) >> 7;
  int colTiles = (Nc + 127) >> 7;
  int rpx = (rowTiles + 7) >> 3;
  return 8 * rpx * colTiles;
}

extern "C" void kernel_launch(void* const* d_in, const int* in_sizes, int n_in,
                              void* d_out, int out_size, void* d_ws, size_t ws_size,
                              hipStream_t stream) {
  const float* x   = (const float*)d_in[0];
  const int*   ei  = (const int*)d_in[1];
  const float* ew  = (const float*)d_in[2];
  const float* W1a = (const float*)d_in[3];
  const float* b1a = (const float*)d_in[4];
  const float* W1b = (const float*)d_in[5];
  const float* b1b = (const float*)d_in[6];
  const float* W1c = (const float*)d_in[7];
  const float* b1c = (const float*)d_in[8];
  const float* g1  = (const float*)d_in[9];
  const float* be1 = (const float*)d_in[10];
  const float* W2a = (const float*)d_in[11];
  const float* b2a = (const float*)d_in[12];
  const float* W2b = (const float*)d_in[13];
  const float* b2b = (const float*)d_in[14];
  const float* W2c = (const float*)d_in[15];
  const float* b2c = (const float*)d_in[16];
  const float* g2  = (const float*)d_in[17];
  const float* be2 = (const float*)d_in[18];
  const float* Wl  = (const float*)d_in[19];
  const float* bl  = (const float*)d_in[20];
  float* out = (float*)d_out;

  const int N = in_sizes[0] / 512;
  const int E = in_sizes[1] / 2;
  const int* row = ei;
  const int* col = ei + E;
  (void)n_in; (void)out_size;

  int eb = (E + 255) / 256;
  int nb = (N + 255) / 256;
  int nb1 = (N + 1023) / 1024;

  // ---- common prefix layout ----
  char* ws = (char*)d_ws;
  size_t o = 0;
  int2*  ePack = (int2*)(ws + o);  o += (size_t)E * 8;
  float* dis   = (float*)(ws + o); o += (size_t)N * 4;
  int*   cnt   = (int*)(ws + o);   o += (size_t)N * 4;
  int*   off   = (int*)(ws + o);   o += (size_t)(N + 4) * 4;
  int*   wptr  = (int*)(ws + o);   o += (size_t)N * 4;
  int*   bsum  = (int*)(ws + o);   o += (size_t)(nb1 + 4) * 4;
  float* sums  = (float*)(ws + o); o += 2400 * 4;
  float* scSh  = (float*)(ws + o); o += 2400 * 4;
  float* bcat1 = (float*)(ws + o); o += 1200 * 4;
  float* bcat2 = (float*)(ws + o); o += 304 * 4;
  o = (o + 255) & ~(size_t)255;
  size_t oCommon = o;

  // ---- plan A layout ----
  size_t oA = oCommon;
  unsigned short* BtL1 = (unsigned short*)(ws + oA); oA += (size_t)1280 * 1536 * 2;
  unsigned short* BtL2 = (unsigned short*)(ws + oA); oA += (size_t)640 * 1216 * 2;
  oA = (oA + 255) & ~(size_t)255;
  unsigned short* h1n = (unsigned short*)(ws + oA); oA += (size_t)N * 1216 * 2;
  oA = (oA + 255) & ~(size_t)255;
  float* h2f = (float*)(ws + oA); oA += (size_t)N * 300 * 4;
  oA = (oA + 255) & ~(size_t)255;
  // region X: Xcat (N x 1536 bf16) in phase 1; Zcat (N x 304) + U1 (N x 104) in phase 2
  unsigned short* Xcat = (unsigned short*)(ws + oA); oA += (size_t)N * 1536 * 2;
  unsigned short* Zcat = Xcat;
  unsigned short* U1 = Xcat + (size_t)N * 304;

  bool planA = (ws_size >= oA);

  // ---- graph prep (both plans) ----
  hipMemsetAsync(dis, 0, (size_t)N * 4, stream);
  hipMemsetAsync(cnt, 0, (size_t)N * 4, stream);
  degcnt_kernel<<<eb, 256, 0, stream>>>(row, col, ew, dis, cnt, E);
  dis_kernel<<<nb, 256, 0, stream>>>(dis, N);
  scan1_kernel<<<nb1, 1024, 0, stream>>>(cnt, off, bsum, N);
  scan2_kernel<<<1, 64, 0, stream>>>(bsum, off, nb1, N);
  scan3_kernel<<<nb, 256, 0, stream>>>(off, bsum, N);
  copy_kernel<<<nb, 256, 0, stream>>>(off, wptr, N);
  fill_kernel<<<eb, 256, 0, stream>>>(row, col, ew, dis, wptr, ePack, E);

  if (planA) {
    // fused weight prep:
    // BtL1 [1280 x 1536]: rows 0-399 W1a (K 0-512), 400-799 W1b (K 0-1024),
    //                     800-1199 W1c (K 0-1536); rest zero.
    // BtL2 [640 x 1216]:  rows 0-99 W2a k0, 100-199 W2b k0, 200-299 W2c k0,
    //                     304-403 W2b k1, 404-503 W2c k1, 504-603 W2c k2; rest zero.
    hipMemsetAsync(BtL1, 0, (size_t)1280 * 1536 * 2, stream);
    hipMemsetAsync(BtL2, 0, (size_t)640 * 1216 * 2, stream);
    wprep_kernel<<<(400 * 512 + 255) / 256, 256, 0, stream>>>(W1a, BtL1, 512, 400, 1536, 0);
    wprep_kernel<<<(400 * 1024 + 255) / 256, 256, 0, stream>>>(W1b, BtL1, 1024, 400, 1536, 400);
    wprep_kernel<<<(400 * 1536 + 255) / 256, 256, 0, stream>>>(W1c, BtL1, 1536, 400, 1536, 800);
    wprep_kernel<<<(100 * 1200 + 255) / 256, 256, 0, stream>>>(W2a, BtL2, 1200, 100, 1216, 0);
    wprep_kernel<<<(100 * 1200 + 255) / 256, 256, 0, stream>>>(W2b, BtL2, 1200, 100, 1216, 100);
    wprep_kernel<<<(100 * 1200 + 255) / 256, 256, 0, stream>>>(W2c, BtL2, 1200, 100, 1216, 200);
    wprep_kernel<<<(100 * 1200 + 255) / 256, 256, 0, stream>>>(W2b + 1200 * 100, BtL2, 1200, 100, 1216, 304);
    wprep_kernel<<<(100 * 1200 + 255) / 256, 256, 0, stream>>>(W2c + 1200 * 100, BtL2, 1200, 100, 1216, 404);
    wprep_kernel<<<(100 * 1200 + 255) / 256, 256, 0, stream>>>(W2c + 2 * 1200 * 100, BtL2, 1200, 100, 1216, 504);
    bcat_kernel<<<(1200 + 255) / 256, 256, 0, stream>>>(b1a, b1b, b1c, bcat1, 400);
    bcat_kernel<<<(300 + 255) / 256, 256, 0, stream>>>(b2a, b2b, b2c, bcat2, 100);
    cast_x_kernel<<<(N * 128 + 255) / 256, 256, 0, stream>>>(x, Xcat, N);
    padzero_kernel<<<(N * 2 + 255) / 256, 256, 0, stream>>>(h1n, N);

    // layer-1 props (XCD-affine chunked): P1 = L x ; P2 = 2 L P1 - x
    int gridP = ((N + 7) / 8) * 8;
    prop_chunk_kernel<<<gridP, 256, 0, stream>>>(Xcat, 1536, 0, 512, -1,
                                                 off, ePack, 1.f, N);
    prop_chunk_kernel<<<gridP, 256, 0, stream>>>(Xcat, 1536, 512, 1024, 0,
                                                 off, ePack, 2.f, N);

    // layer-1 fused GEMM -> h1n (bf16, ld 1216), variable K per col-tile
    int gA = gemm_grid(N, 1200);
    gemm_bf16_kernel<<<gA, 256, 0, stream>>>(Xcat, 1536, BtL1, 1536, N, 1200, 1536,
                                             bcat1, h1n, nullptr, 1216, 0, 0, 1, 0);

    // BN1 + ReLU on h1n
    hipMemsetAsync(sums, 0, 2400 * 4, stream);
    dim3 s1g((1200 + 255) / 256, (N + 255) / 256);
    bn_stats_bf16_kernel<<<s1g, 256, 0, stream>>>(h1n, 1216, 1200, N, sums);
    scsh_kernel<<<(1200 + 255) / 256, 256, 0, stream>>>(sums, g1, be1, 1.f / (float)N, 1200, scSh);
    bn_apply_bf16_kernel<<<((size_t)N * 150 + 255) / 256, 256, 0, stream>>>(
        h1n, 1216, 150, N, scSh, 1200, 1);

    // layer-2 fused GEMM: cols 0-299 -> h2f fp32 (+bias), cols 304-607 -> Zcat bf16
    int gB = gemm_grid(N, 608);
    gemm_bf16_kernel<<<gB, 256, 0, stream>>>(h1n, 1216, BtL2, 1216, N, 608, 1216,
                                             bcat2, Zcat, h2f, 0, 0, 0, 0, 1);

    // commuted props
    prop_z_kernel<<<N, 64, 0, stream>>>(Zcat, off, ePack, h2f, U1);
    prop_u_kernel<<<N, 64, 0, stream>>>(U1, off, ePack, Zcat, h2f);

    // BN2 stats -> scSh; apply fused into final
    hipMemsetAsync(sums, 0, 2400 * 4, stream);
    dim3 s2g((300 + 255) / 256, (N + 255) / 256);
    bn_stats_kernel<<<s2g, 256, 0, stream>>>(h2f, 300, N, sums);
    scsh_kernel<<<(300 + 255) / 256, 256, 0, stream>>>(sums, g2, be2, 1.f / (float)N, 300, scSh);
    final_bn_kernel<<<nb, 256, 0, stream>>>(h2f, scSh, Wl, bl, out, N);
    return;
  }

  // ================= PLAN B (fp32 fallback) =================
  size_t oB = oCommon;
  float* h2 = (float*)(ws + oB); oB += (size_t)N * 300 * 4;
  oB = (oB + 255) & ~(size_t)255;
  float* h1 = (float*)(ws + oB); oB += (size_t)N * 1200 * 4;
  oB = (oB + 255) & ~(size_t)255;
  size_t avail = (ws_size > oB) ? (ws_size - oB) : 0;
  int C1 = 64;
  { const int opts[4] = {512, 256, 128, 64};
    for (int i = 0; i < 4; i++)
      if ((size_t)2 * N * opts[i] * 4 <= avail) { C1 = opts[i]; break; } }
  int C2 = 100;
  { const int opts[6] = {1200, 600, 400, 300, 200, 100};
    for (int i = 0; i < 6; i++)
      if ((size_t)2 * N * opts[i] * 4 <= avail) { C2 = opts[i]; break; } }
  int maxC = C1 > C2 ? C1 : C2;
  float* S1 = (float*)(ws + oB);
  float* S2 = S1 + (size_t)N * maxC;

  dim3 g1d((400 + BN - 1) / BN, (N + BM - 1) / BM);
  gemm_kernel<<<g1d, 256, 0, stream>>>(x, 512, W1a, 400, h1, 1200, 0,   N, 400, 512, b1a, 0);
  gemm_kernel<<<g1d, 256, 0, stream>>>(x, 512, W1b, 400, h1, 1200, 400, N, 400, 512, b1b, 0);
  gemm_kernel<<<g1d, 256, 0, stream>>>(x, 512, W1c, 400, h1, 1200, 800, N, 400, 512, b1c, 0);
  for (int c = 0; c < 512; c += C1) {
    int D4 = C1 / 4;
    int bt = ((D4 + 63) / 64) * 64;
    prop_kernel<<<N, bt, 0, stream>>>(x + c, 128, D4, off, ePack, S1, D4, nullptr, 0, 1.f);
    gemm_kernel<<<g1d, 256, 0, stream>>>(S1, C1, W1b + (size_t)(512 + c) * 400, 400, h1, 1200, 400, N, 400, C1, nullptr, 1);
    gemm_kernel<<<g1d, 256, 0, stream>>>(S1, C1, W1c + (size_t)(512 + c) * 400, 400, h1, 1200, 800, N, 400, C1, nullptr, 1);
    prop_kernel<<<N, bt, 0, stream>>>(S1, D4, D4, off, ePack, S2, D4, x + c, 128, 2.f);
    gemm_kernel<<<g1d, 256, 0, stream>>>(S2, C1, W1c + (size_t)(2 * 512 + c) * 400, 400, h1, 1200, 800, N, 400, C1, nullptr, 1);
  }

  hipMemsetAsync(sums, 0, 2400 * 4, stream);
  dim3 s1g((1200 + 255) / 256, (N + 255) / 256);
  bn_stats_kernel<<<s1g, 256, 0, stream>>>(h1, 1200, N, sums);
  dim3 a1g((300 + 63) / 64, (N + 255) / 256);
  bn_apply_kernel<<<a1g, 64, 0, stream>>>(h1, 1200, N, sums, g1, be1, 1.f / (float)N, 1);

  dim3 g2d((100 + BN - 1) / BN, (N + BM - 1) / BM);
  gemm_kernel<<<g2d, 256, 0, stream>>>(h1, 1200, W2a, 100, h2, 300, 0,   N, 100, 1200, b2a, 0);
  gemm_kernel<<<g2d, 256, 0, stream>>>(h1, 1200, W2b, 100, h2, 300, 100, N, 100, 1200, b2b, 0);
  gemm_kernel<<<g2d, 256, 0, stream>>>(h1, 1200, W2c, 100, h2, 300, 200, N, 100, 1200, b2c, 0);
  for (int c = 0; c < 1200; c += C2) {
    int D4 = C2 / 4;
    int bt = ((D4 + 63) / 64) * 64;
    prop_kernel<<<N, bt, 0, stream>>>(h1 + c, 300, D4, off, ePack, S1, D4, nullptr, 0, 1.f);
    gemm_kernel<<<g2d, 256, 0, stream>>>(S1, C2, W2b + (size_t)(1200 + c) * 100, 100, h2, 300, 100, N, 100, C2, nullptr, 1);
    gemm_kernel<<<g2d, 256, 0, stream>>>(S1, C2, W2c + (size_t)(1200 + c) * 100, 100, h2, 300, 200, N, 100, C2, nullptr, 1);
    prop_kernel<<<N, bt, 0, stream>>>(S1, D4, D4, off, ePack, S2, D4, h1 + c, 300, 2.f);
    gemm_kernel<<<g2d, 256, 0, stream>>>(S2, C2, W2c + (size_t)(2 * 1200 + c) * 100, 100, h2, 300, 200, N, 100, C2, nullptr, 1);
  }

  hipMemsetAsync(sums, 0, 2400 * 4, stream);
  dim3 s2g((300 + 255) / 256, (N + 255) / 256);
  bn_stats_kernel<<<s2g, 256, 0, stream>>>(h2, 300, N, sums);
  dim3 a2g((75 + 63) / 64, (N + 255) / 256);
  bn_apply_kernel<<<a2g, 64, 0, stream>>>(h2, 300, N, sums, g2, be2, 1.f / (float)N, 0);

  final_kernel<<<nb, 256, 0, stream>>>(h2, Wl, bl, out, N);
}

// Round 8
// 1677.680 us; speedup vs baseline: 1.6185x; 1.0049x over previous
//
#include <hip/hip_runtime.h>
#include <math.h>

#define EPSB 1e-5f

typedef __attribute__((ext_vector_type(8))) short short8;
typedef __attribute__((ext_vector_type(4))) float floatx4;
typedef __attribute__((ext_vector_type(2))) float floatx2;

__device__ inline float bf2f(unsigned short h) {
  union { unsigned int u; float f; } v; v.u = ((unsigned int)h) << 16; return v.f;
}
__device__ inline unsigned short f2bf(float f) {
  union { float f; unsigned int u; } v; v.f = f;
  unsigned int r = v.u + 0x7fffu + ((v.u >> 16) & 1u);  // RNE
  return (unsigned short)(r >> 16);
}

// async global->LDS 16B (wave-uniform LDS base + lane*16; global addr per-lane)
__device__ __forceinline__ void gl2lds16(const unsigned short* g, unsigned short* l) {
  __builtin_amdgcn_global_load_lds(
      (const __attribute__((address_space(1))) unsigned int*)g,
      (__attribute__((address_space(3))) unsigned int*)l, 16, 0, 0);
}

// packed bf16x8 accumulate: a[j] += {lo,hi}(g[j]) * wv  via v_pk_fma_f32
__device__ __forceinline__ void pk4(floatx2* a, uint4 g, floatx2 wv) {
  unsigned int u[4] = {g.x, g.y, g.z, g.w};
#pragma unroll
  for (int j = 0; j < 4; j++) {
    union { unsigned int q; float f; } lo, hi;
    lo.q = u[j] << 16;
    hi.q = u[j] & 0xffff0000u;
    floatx2 v; v[0] = lo.f; v[1] = hi.f;
    asm("v_pk_fma_f32 %0, %1, %2, %0" : "+v"(a[j]) : "v"(v), "v"(wv));
  }
}

// ---------------- graph prep ----------------

__global__ void degcnt_kernel(const int* __restrict__ row, const int* __restrict__ col,
                              const float* __restrict__ ew,
                              float* __restrict__ deg, int* __restrict__ cnt, int E) {
  int e = blockIdx.x * blockDim.x + threadIdx.x;
  if (e < E) {
    atomicAdd(&deg[row[e]], ew[e]);
    atomicAdd(&cnt[col[e]], 1);
  }
}

__global__ void dis_kernel(float* deg, int n) {
  int i = blockIdx.x * blockDim.x + threadIdx.x;
  if (i < n) { float d = deg[i]; deg[i] = d > 0.f ? rsqrtf(d) : 0.f; }
}

__global__ __launch_bounds__(1024) void scan1_kernel(const int* __restrict__ cnt,
                                                     int* __restrict__ off,
                                                     int* __restrict__ bsum, int n) {
  __shared__ int buf[1024];
  int tid = threadIdx.x;
  int idx = blockIdx.x * 1024 + tid;
  int v = (idx < n) ? cnt[idx] : 0;
  buf[tid] = v;
  __syncthreads();
  for (int s = 1; s < 1024; s <<= 1) {
    int t = (tid >= s) ? buf[tid - s] : 0;
    __syncthreads();
    if (tid >= s) buf[tid] += t;
    __syncthreads();
  }
  if (idx < n) off[idx] = buf[tid] - v;  // block-local exclusive
  if (tid == 1023) bsum[blockIdx.x] = buf[1023];
}

__global__ void scan2_kernel(int* __restrict__ bsum, int* __restrict__ off,
                             int nb, int n) {
  if (threadIdx.x == 0 && blockIdx.x == 0) {
    int run = 0;
    for (int k = 0; k < nb; k++) { int t = bsum[k]; bsum[k] = run; run += t; }
    off[n] = run;
  }
}

__global__ void scan3_kernel(int* __restrict__ off, const int* __restrict__ bsum, int n) {
  int i = blockIdx.x * blockDim.x + threadIdx.x;
  if (i < n) off[i] += bsum[i >> 10];
}

__global__ void copy_kernel(const int* __restrict__ src, int* __restrict__ dst, int n) {
  int i = blockIdx.x * blockDim.x + threadIdx.x;
  if (i < n) dst[i] = src[i];
}

// packed edge record: .x = source row index, .y = float bits of norm weight
__global__ void fill_kernel(const int* __restrict__ row, const int* __restrict__ col,
                            const float* __restrict__ ew, const float* __restrict__ dis,
                            int* __restrict__ wptr, int2* __restrict__ ePack, int E) {
  int e = blockIdx.x * blockDim.x + threadIdx.x;
  if (e < E) {
    int r = row[e], c = col[e];
    int p = atomicAdd(&wptr[c], 1);
    float nv = -dis[r] * ew[e] * dis[c];
    ePack[p] = make_int2(r, __float_as_int(nv));
  }
}

// ================= PLAN A (bf16 + MFMA) =================

// cast x (N x 512 fp32) into Xcat cols [0,512) (ld 1536, bf16)
__global__ void cast_x_kernel(const float* __restrict__ x, unsigned short* __restrict__ xb,
                              int N) {
  int idx = blockIdx.x * blockDim.x + threadIdx.x;
  if (idx >= N * 128) return;
  int row = idx >> 7, c4 = idx & 127;
  float4 v = *reinterpret_cast<const float4*>(x + (size_t)row * 512 + c4 * 4);
  union { unsigned int u[2]; } p;
  p.u[0] = (unsigned int)f2bf(v.x) | ((unsigned int)f2bf(v.y) << 16);
  p.u[1] = (unsigned int)f2bf(v.z) | ((unsigned int)f2bf(v.w) << 16);
  *reinterpret_cast<uint2*>(xb + (size_t)row * 1536 + c4 * 4) = make_uint2(p.u[0], p.u[1]);
}

// transpose+cast weights: W[k][n] fp32 (n fastest) -> Bt[rowOff+n][k] bf16 (ld ldBt)
__global__ void wprep_kernel(const float* __restrict__ W, unsigned short* __restrict__ Bt,
                             int Ktot, int Nout, int ldBt, int rowOff) {
  int idx = blockIdx.x * blockDim.x + threadIdx.x;
  if (idx >= Ktot * Nout) return;
  int k = idx / Nout, n = idx - k * Nout;
  Bt[(size_t)(rowOff + n) * ldBt + k] = f2bf(W[idx]);
}

// zero pad cols [1200,1216) of h1n (ld 1216)
__global__ void padzero_kernel(unsigned short* __restrict__ h, int N) {
  int i = blockIdx.x * blockDim.x + threadIdx.x;
  if (i >= N * 2) return;
  *reinterpret_cast<uint4*>(h + (size_t)(i >> 1) * 1216 + 1200 + (i & 1) * 8) =
      make_uint4(0, 0, 0, 0);
}

// concat 3 segments of length seg into dst
__global__ void bcat_kernel(const float* __restrict__ a, const float* __restrict__ b,
                            const float* __restrict__ c, float* __restrict__ dst, int seg) {
  int i = blockIdx.x * blockDim.x + threadIdx.x;
  if (i >= 3 * seg) return;
  float v;
  if (i < seg) v = a[i];
  else if (i < 2 * seg) v = b[i - seg];
  else v = c[i - 2 * seg];
  dst[i] = v;
}

// ---- XCD-affine chunked layer-1 prop (benched floor: 177 us — do not touch) ----
__global__ __launch_bounds__(256) void prop_chunk_kernel(
    unsigned short* __restrict__ base, int ld,
    int srcCol, int dstCol, int subCol,    // subCol < 0 => no sub
    const int* __restrict__ off, const int2* __restrict__ ePack,
    float scale, int N) {
  int chunk = blockIdx.x & 7;
  int g = blockIdx.x >> 3;
  int tid = threadIdx.x;
  int slot = (tid >> 3) & 3;
  int c8 = tid & 7;
  int v = g * 8 + (tid >> 5);
  bool valid = v < N;
  int vv = valid ? v : N - 1;
  int co = chunk * 64 + c8 * 8;
  const unsigned short* src = base + srcCol + co;
  int s = off[vv], e = off[vv + 1];
  int len = e - s;
  int s0 = s + (len * slot >> 2);
  int e0 = s + (len * (slot + 1) >> 2);
  floatx2 a2[4] = {}, b2[4] = {};
  int i = s0;
  for (; i + 3 < e0; i += 4) {
    int2 p0 = ePack[i];
    int2 p1 = ePack[i + 1];
    int2 p2 = ePack[i + 2];
    int2 p3 = ePack[i + 3];
    uint4 g0 = *reinterpret_cast<const uint4*>(src + (size_t)p0.x * ld);
    uint4 g1 = *reinterpret_cast<const uint4*>(src + (size_t)p1.x * ld);
    uint4 g2 = *reinterpret_cast<const uint4*>(src + (size_t)p2.x * ld);
    uint4 g3 = *reinterpret_cast<const uint4*>(src + (size_t)p3.x * ld);
    floatx2 w0; w0[0] = w0[1] = __int_as_float(p0.y);
    floatx2 w1; w1[0] = w1[1] = __int_as_float(p1.y);
    floatx2 w2; w2[0] = w2[1] = __int_as_float(p2.y);
    floatx2 w3; w3[0] = w3[1] = __int_as_float(p3.y);
    pk4(a2, g0, w0);
    pk4(b2, g1, w1);
    pk4(a2, g2, w2);
    pk4(b2, g3, w3);
  }
  for (; i < e0; i++) {
    int2 p = ePack[i];
    uint4 gg = *reinterpret_cast<const uint4*>(src + (size_t)p.x * ld);
    floatx2 wv; wv[0] = wv[1] = __int_as_float(p.y);
    pk4(a2, gg, wv);
  }
  float a[8];
#pragma unroll
  for (int j = 0; j < 4; j++) {
    a[2 * j]     = a2[j][0] + b2[j][0];
    a[2 * j + 1] = a2[j][1] + b2[j][1];
  }
#pragma unroll
  for (int j = 0; j < 8; j++) {
    a[j] += __shfl_xor(a[j], 8);
    a[j] += __shfl_xor(a[j], 16);
  }
  if (slot != 0 || !valid) return;
  if (subCol >= 0) {
    uint4 sv = *reinterpret_cast<const uint4*>(base + subCol + co + (size_t)v * ld);
    a[0] = scale * a[0] - bf2f((unsigned short)(sv.x & 0xffff));
    a[1] = scale * a[1] - bf2f((unsigned short)(sv.x >> 16));
    a[2] = scale * a[2] - bf2f((unsigned short)(sv.y & 0xffff));
    a[3] = scale * a[3] - bf2f((unsigned short)(sv.y >> 16));
    a[4] = scale * a[4] - bf2f((unsigned short)(sv.z & 0xffff));
    a[5] = scale * a[5] - bf2f((unsigned short)(sv.z >> 16));
    a[6] = scale * a[6] - bf2f((unsigned short)(sv.w & 0xffff));
    a[7] = scale * a[7] - bf2f((unsigned short)(sv.w >> 16));
  }
  uint4 o;
  o.x = (unsigned int)f2bf(a[0]) | ((unsigned int)f2bf(a[1]) << 16);
  o.y = (unsigned int)f2bf(a[2]) | ((unsigned int)f2bf(a[3]) << 16);
  o.z = (unsigned int)f2bf(a[4]) | ((unsigned int)f2bf(a[5]) << 16);
  o.w = (unsigned int)f2bf(a[6]) | ((unsigned int)f2bf(a[7]) << 16);
  *reinterpret_cast<uint4*>(base + dstCol + co + (size_t)v * ld) = o;
}

// ---- commuted layer-2 props ----
__global__ void prop_z_kernel(const unsigned short* __restrict__ Zcat,
                              const int* __restrict__ off, const int2* __restrict__ ePack,
                              float* __restrict__ h2f, unsigned short* __restrict__ U1) {
  int v = blockIdx.x;
  int f8 = threadIdx.x;
  if (f8 >= 38) return;
  int s = off[v], e = off[v + 1];
  floatx2 a2[4] = {}, b2[4] = {};
  int i = s;
  for (; i + 3 < e; i += 4) {
    int2 p0 = ePack[i];
    int2 p1 = ePack[i + 1];
    int2 p2 = ePack[i + 2];
    int2 p3 = ePack[i + 3];
    uint4 g0 = *reinterpret_cast<const uint4*>(Zcat + (size_t)p0.x * 304 + f8 * 8);
    uint4 g1 = *reinterpret_cast<const uint4*>(Zcat + (size_t)p1.x * 304 + f8 * 8);
    uint4 g2 = *reinterpret_cast<const uint4*>(Zcat + (size_t)p2.x * 304 + f8 * 8);
    uint4 g3 = *reinterpret_cast<const uint4*>(Zcat + (size_t)p3.x * 304 + f8 * 8);
    floatx2 w0; w0[0] = w0[1] = __int_as_float(p0.y);
    floatx2 w1; w1[0] = w1[1] = __int_as_float(p1.y);
    floatx2 w2; w2[0] = w2[1] = __int_as_float(p2.y);
    floatx2 w3; w3[0] = w3[1] = __int_as_float(p3.y);
    pk4(a2, g0, w0);
    pk4(b2, g1, w1);
    pk4(a2, g2, w2);
    pk4(b2, g3, w3);
  }
  for (; i < e; i++) {
    int2 p = ePack[i];
    uint4 raw = *reinterpret_cast<const uint4*>(Zcat + (size_t)p.x * 304 + f8 * 8);
    floatx2 wv; wv[0] = wv[1] = __int_as_float(p.y);
    pk4(a2, raw, wv);
  }
  float a[8];
#pragma unroll
  for (int j = 0; j < 4; j++) {
    a[2 * j]     = a2[j][0] + b2[j][0];
    a[2 * j + 1] = a2[j][1] + b2[j][1];
  }
  if (f8 < 25) {
    float* p = h2f + (size_t)v * 300 + 100 + f8 * 8;
#pragma unroll
    for (int j = 0; j < 8; j++) p[j] += a[j];
  } else {
    uint4 o;
    o.x = (unsigned int)f2bf(a[0]) | ((unsigned int)f2bf(a[1]) << 16);
    o.y = (unsigned int)f2bf(a[2]) | ((unsigned int)f2bf(a[3]) << 16);
    o.z = (unsigned int)f2bf(a[4]) | ((unsigned int)f2bf(a[5]) << 16);
    o.w = (unsigned int)f2bf(a[6]) | ((unsigned int)f2bf(a[7]) << 16);
    *reinterpret_cast<uint4*>(U1 + (size_t)v * 104 + (f8 - 25) * 8) = o;
  }
}

__global__ void prop_u_kernel(const unsigned short* __restrict__ U1,
                              const int* __restrict__ off, const int2* __restrict__ ePack,
                              const unsigned short* __restrict__ Zcat,
                              float* __restrict__ h2f) {
  int v = blockIdx.x;
  int f8 = threadIdx.x;
  if (f8 >= 13) return;
  int s = off[v], e = off[v + 1];
  floatx2 a2[4] = {}, b2[4] = {};
  int i = s;
  for (; i + 3 < e; i += 4) {
    int2 p0 = ePack[i];
    int2 p1 = ePack[i + 1];
    int2 p2 = ePack[i + 2];
    int2 p3 = ePack[i + 3];
    uint4 g0 = *reinterpret_cast<const uint4*>(U1 + (size_t)p0.x * 104 + f8 * 8);
    uint4 g1 = *reinterpret_cast<const uint4*>(U1 + (size_t)p1.x * 104 + f8 * 8);
    uint4 g2 = *reinterpret_cast<const uint4*>(U1 + (size_t)p2.x * 104 + f8 * 8);
    uint4 g3 = *reinterpret_cast<const uint4*>(U1 + (size_t)p3.x * 104 + f8 * 8);
    floatx2 w0; w0[0] = w0[1] = __int_as_float(p0.y);
    floatx2 w1; w1[0] = w1[1] = __int_as_float(p1.y);
    floatx2 w2; w2[0] = w2[1] = __int_as_float(p2.y);
    floatx2 w3; w3[0] = w3[1] = __int_as_float(p3.y);
    pk4(a2, g0, w0);
    pk4(b2, g1, w1);
    pk4(a2, g2, w2);
    pk4(b2, g3, w3);
  }
  for (; i < e; i++) {
    int2 p = ePack[i];
    uint4 raw = *reinterpret_cast<const uint4*>(U1 + (size_t)p.x * 104 + f8 * 8);
    floatx2 wv; wv[0] = wv[1] = __int_as_float(p.y);
    pk4(a2, raw, wv);
  }
  float a[8];
#pragma unroll
  for (int j = 0; j < 4; j++) {
    a[2 * j]     = a2[j][0] + b2[j][0];
    a[2 * j + 1] = a2[j][1] + b2[j][1];
  }
  const unsigned short* z2 = Zcat + (size_t)v * 304 + 200;
  float* p = h2f + (size_t)v * 300 + 200;
#pragma unroll
  for (int j = 0; j < 8; j++) {
    int c = f8 * 8 + j;
    if (c < 100) p[c] += 2.f * a[j] - bf2f(z2[c]);
  }
}

// ---- specialized bf16 MFMA GEMMs (m97 structure + XCD row-affine remap) ----
// Split into single-purpose kernels: the merged variant hit 72 VGPR and fell
// off the 128-reg occupancy tier (28.5% occ, MfmaUtil 21%). Hard-coded
// geometry keeps each at the R2-R6 register footprint (~40 arch VGPR).

// L1: Xcat (lda 1536) x BtL1 (ldb 1536) -> h1n bf16 (ld 1216), Nc=1200,
// per-col-tile K: tiles 0-2 K=512, 3-5 K=1024, 6-9 K=1536.
__global__ __launch_bounds__(256) void gemm_l1_kernel(
    const unsigned short* __restrict__ A,
    const unsigned short* __restrict__ Bt,
    int M, const float* __restrict__ bias,
    unsigned short* __restrict__ Cb) {
  __shared__ __align__(16) unsigned short As[128 * 32];
  __shared__ __align__(16) unsigned short Bs[128 * 32];
  const int colTiles = 10;
  int rowTiles = (M + 127) >> 7;
  int L = blockIdx.x;
  int xcd = L & 7, slot = L >> 3;
  int rpx = (rowTiles + 7) >> 3;
  int rloc = slot / colTiles;
  int ct = slot - rloc * colTiles;
  int rt = xcd * rpx + rloc;
  if (rt >= rowTiles) return;
  int row0 = rt << 7, col0 = ct << 7;
  int Kt = (ct < 3) ? 512 : ((ct < 6) ? 1024 : 1536);

  int tid = threadIdx.x;
  int wave = tid >> 6, lane = tid & 63;
  int q = lane >> 4, mn = lane & 15;
  int wr = wave >> 1, wc = wave & 1;
  floatx4 acc[4][4] = {};

  const unsigned short* ga[2];
  const unsigned short* gb[2];
  unsigned short* la[2];
  unsigned short* lb[2];
#pragma unroll
  for (int j = 0; j < 2; j++) {
    int c = j * 256 + tid;
    int r = c >> 2, cw = (c & 3) * 8;
    int gr = row0 + r; if (gr > M - 1) gr = M - 1;
    ga[j] = A + (size_t)gr * 1536 + cw;
    gb[j] = Bt + (size_t)(col0 + r) * 1536 + cw;
    la[j] = &As[(j * 256 + wave * 64) * 8];
    lb[j] = &Bs[(j * 256 + wave * 64) * 8];
  }

  for (int k0 = 0; k0 < Kt; k0 += 32) {
#pragma unroll
    for (int j = 0; j < 2; j++) {
      gl2lds16(ga[j] + k0, la[j]);
      gl2lds16(gb[j] + k0, lb[j]);
    }
    __syncthreads();
    short8 af[4], bf[4];
#pragma unroll
    for (int i = 0; i < 4; i++) {
      af[i] = *reinterpret_cast<const short8*>(&As[(wr * 64 + i * 16 + mn) * 32 + q * 8]);
      bf[i] = *reinterpret_cast<const short8*>(&Bs[(wc * 64 + i * 16 + mn) * 32 + q * 8]);
    }
#pragma unroll
    for (int mi = 0; mi < 4; mi++)
#pragma unroll
      for (int ni = 0; ni < 4; ni++)
        acc[mi][ni] = __builtin_amdgcn_mfma_f32_16x16x32_bf16(af[mi], bf[ni], acc[mi][ni], 0, 0, 0);
    __syncthreads();
  }

#pragma unroll
  for (int mi = 0; mi < 4; mi++) {
#pragma unroll
    for (int ni = 0; ni < 4; ni++) {
      int gcol = col0 + wc * 64 + ni * 16 + mn;
      if (gcol >= 1200) continue;
      float b = bias[gcol];
#pragma unroll
      for (int r = 0; r < 4; r++) {
        int grow = row0 + wr * 64 + mi * 16 + q * 4 + r;
        if (grow >= M) continue;
        Cb[(size_t)grow * 1216 + gcol] = f2bf(acc[mi][ni][r] + b);
      }
    }
  }
}

// L2: h1n (lda 1216) x BtL2 (ldb 1216), Nc=608, K=1216, dual epilogue:
// gcol<300 -> h2f fp32 (ld 300, +bias); gcol>=304 -> Zcat bf16 (ld 304).
__global__ __launch_bounds__(256) void gemm_l2_kernel(
    const unsigned short* __restrict__ A,
    const unsigned short* __restrict__ Bt,
    int M, const float* __restrict__ bias,
    unsigned short* __restrict__ Cb, float* __restrict__ Cf) {
  __shared__ __align__(16) unsigned short As[128 * 32];
  __shared__ __align__(16) unsigned short Bs[128 * 32];
  const int colTiles = 5;
  int rowTiles = (M + 127) >> 7;
  int L = blockIdx.x;
  int xcd = L & 7, slot = L >> 3;
  int rpx = (rowTiles + 7) >> 3;
  int rloc = slot / colTiles;
  int ct = slot - rloc * colTiles;
  int rt = xcd * rpx + rloc;
  if (rt >= rowTiles) return;
  int row0 = rt << 7, col0 = ct << 7;

  int tid = threadIdx.x;
  int wave = tid >> 6, lane = tid & 63;
  int q = lane >> 4, mn = lane & 15;
  int wr = wave >> 1, wc = wave & 1;
  floatx4 acc[4][4] = {};

  const unsigned short* ga[2];
  const unsigned short* gb[2];
  unsigned short* la[2];
  unsigned short* lb[2];
#pragma unroll
  for (int j = 0; j < 2; j++) {
    int c = j * 256 + tid;
    int r = c >> 2, cw = (c & 3) * 8;
    int gr = row0 + r; if (gr > M - 1) gr = M - 1;
    ga[j] = A + (size_t)gr * 1216 + cw;
    int gn = col0 + r; if (gn > 607) gn = 607;
    gb[j] = Bt + (size_t)gn * 1216 + cw;
    la[j] = &As[(j * 256 + wave * 64) * 8];
    lb[j] = &Bs[(j * 256 + wave * 64) * 8];
  }

  for (int k0 = 0; k0 < 1216; k0 += 32) {
#pragma unroll
    for (int j = 0; j < 2; j++) {
      gl2lds16(ga[j] + k0, la[j]);
      gl2lds16(gb[j] + k0, lb[j]);
    }
    __syncthreads();
    short8 af[4], bf[4];
#pragma unroll
    for (int i = 0; i < 4; i++) {
      af[i] = *reinterpret_cast<const short8*>(&As[(wr * 64 + i * 16 + mn) * 32 + q * 8]);
      bf[i] = *reinterpret_cast<const short8*>(&Bs[(wc * 64 + i * 16 + mn) * 32 + q * 8]);
    }
#pragma unroll
    for (int mi = 0; mi < 4; mi++)
#pragma unroll
      for (int ni = 0; ni < 4; ni++)
        acc[mi][ni] = __builtin_amdgcn_mfma_f32_16x16x32_bf16(af[mi], bf[ni], acc[mi][ni], 0, 0, 0);
    __syncthreads();
  }

#pragma unroll
  for (int mi = 0; mi < 4; mi++) {
#pragma unroll
    for (int ni = 0; ni < 4; ni++) {
      int gcol = col0 + wc * 64 + ni * 16 + mn;
      if (gcol < 300) {
        float b = bias[gcol];
#pragma unroll
        for (int r = 0; r < 4; r++) {
          int grow = row0 + wr * 64 + mi * 16 + q * 4 + r;
          if (grow >= M) continue;
          Cf[(size_t)grow * 300 + gcol] = acc[mi][ni][r] + b;
        }
      } else if (gcol >= 304 && gcol < 608) {
#pragma unroll
        for (int r = 0; r < 4; r++) {
          int grow = row0 + wr * 64 + mi * 16 + q * 4 + r;
          if (grow >= M) continue;
          Cb[(size_t)grow * 304 + (gcol - 304)] = f2bf(acc[mi][ni][r]);
        }
      }
    }
  }
}

// BN stats over bf16 matrix (strided)
__global__ void bn_stats_bf16_kernel(const unsigned short* __restrict__ h, int ld, int C,
                                     int N, float* __restrict__ sums) {
  int c = blockIdx.x * blockDim.x + threadIdx.x;
  if (c >= C) return;
  int r0 = blockIdx.y * 256;
  int r1 = min(N, r0 + 256);
  float s = 0.f, s2 = 0.f;
  for (int r = r0; r < r1; r++) {
    float v = bf2f(h[(size_t)r * ld + c]);
    s += v; s2 += v * v;
  }
  atomicAdd(&sums[c], s);
  atomicAdd(&sums[C + c], s2);
}

__global__ void scsh_kernel(const float* __restrict__ sums, const float* __restrict__ g,
                            const float* __restrict__ beta, float invN, int C,
                            float* __restrict__ scSh) {
  int c = blockIdx.x * blockDim.x + threadIdx.x;
  if (c >= C) return;
  float mu = sums[c] * invN;
  float var = sums[C + c] * invN - mu * mu;
  float s = rsqrtf(var + EPSB) * g[c];
  scSh[c] = s;
  scSh[C + c] = beta[c] - mu * s;
}

// BN apply (+optional relu) on bf16 matrix, 8 cols/thread
__global__ void bn_apply_bf16_kernel(unsigned short* __restrict__ h, int ld, int C8, int N,
                                     const float* __restrict__ scSh, int Cfull, int relu) {
  int idx = blockIdx.x * blockDim.x + threadIdx.x;
  if (idx >= N * C8) return;
  int row = idx / C8, c8 = idx - row * C8;
  unsigned short* p = h + (size_t)row * ld + c8 * 8;
  uint4 raw = *reinterpret_cast<uint4*>(p);
  float v[8];
  v[0] = bf2f((unsigned short)(raw.x & 0xffff)); v[1] = bf2f((unsigned short)(raw.x >> 16));
  v[2] = bf2f((unsigned short)(raw.y & 0xffff)); v[3] = bf2f((unsigned short)(raw.y >> 16));
  v[4] = bf2f((unsigned short)(raw.z & 0xffff)); v[5] = bf2f((unsigned short)(raw.z >> 16));
  v[6] = bf2f((unsigned short)(raw.w & 0xffff)); v[7] = bf2f((unsigned short)(raw.w >> 16));
#pragma unroll
  for (int j = 0; j < 8; j++) {
    int c = c8 * 8 + j;
    float o = v[j] * scSh[c] + scSh[Cfull + c];
    if (relu) o = fmaxf(o, 0.f);
    v[j] = o;
  }
  uint4 o;
  o.x = (unsigned int)f2bf(v[0]) | ((unsigned int)f2bf(v[1]) << 16);
  o.y = (unsigned int)f2bf(v[2]) | ((unsigned int)f2bf(v[3]) << 16);
  o.z = (unsigned int)f2bf(v[4]) | ((unsigned int)f2bf(v[5]) << 16);
  o.w = (unsigned int)f2bf(v[6]) | ((unsigned int)f2bf(v[7]) << 16);
  *reinterpret_cast<uint4*>(p) = o;
}

// fp32 BN pieces
__global__ void bn_stats_kernel(const float* __restrict__ h, int C, int N,
                                float* __restrict__ sums) {
  int c = blockIdx.x * blockDim.x + threadIdx.x;
  if (c >= C) return;
  int r0 = blockIdx.y * 256;
  int r1 = min(N, r0 + 256);
  float s = 0.f, s2 = 0.f;
  for (int r = r0; r < r1; r++) {
    float v = h[(size_t)r * C + c];
    s += v; s2 += v * v;
  }
  atomicAdd(&sums[c], s);
  atomicAdd(&sums[C + c], s2);
}

__global__ void bn_apply_kernel(float* __restrict__ h, int C, int N,
                                const float* __restrict__ sums, const float* __restrict__ g,
                                const float* __restrict__ beta, float invN, int relu) {
  int C4 = C >> 2;
  int c4 = blockIdx.x * blockDim.x + threadIdx.x;
  if (c4 >= C4) return;
  float sc[4], sh[4];
#pragma unroll
  for (int j = 0; j < 4; j++) {
    int c = c4 * 4 + j;
    float mu = sums[c] * invN;
    float var = sums[C + c] * invN - mu * mu;
    float s = rsqrtf(var + EPSB) * g[c];
    sc[j] = s; sh[j] = beta[c] - mu * s;
  }
  int r0 = blockIdx.y * 256, r1 = min(N, r0 + 256);
  for (int r = r0; r < r1; r++) {
    float4* p = reinterpret_cast<float4*>(h + (size_t)r * C) + c4;
    float4 v = *p;
    v.x = v.x * sc[0] + sh[0]; v.y = v.y * sc[1] + sh[1];
    v.z = v.z * sc[2] + sh[2]; v.w = v.w * sc[3] + sh[3];
    if (relu) {
      v.x = fmaxf(v.x, 0.f); v.y = fmaxf(v.y, 0.f);
      v.z = fmaxf(v.z, 0.f); v.w = fmaxf(v.w, 0.f);
    }
    *p = v;
  }
}

// ---------------- final: BN2-apply fused + linear + log_softmax ----------------

__global__ __launch_bounds__(256) void final_bn_kernel(const float* __restrict__ h2,
                                                       const float* __restrict__ scSh,
                                                       const float* __restrict__ Wl,
                                                       const float* __restrict__ bl,
                                                       float* __restrict__ out, int N) {
  __shared__ float Ws[3000];
  __shared__ float S[600];
  for (int i = threadIdx.x; i < 3000; i += 256) Ws[i] = Wl[i];
  for (int i = threadIdx.x; i < 600; i += 256) S[i] = scSh[i];
  __syncthreads();
  int r = blockIdx.x * blockDim.x + threadIdx.x;
  if (r >= N) return;
  float acc[10];
#pragma unroll
  for (int c = 0; c < 10; c++) acc[c] = bl[c];
  const float* hr = h2 + (size_t)r * 300;
  for (int k = 0; k < 300; k++) {
    float x = hr[k] * S[k] + S[300 + k];
#pragma unroll
    for (int c = 0; c < 10; c++) acc[c] += x * Ws[k * 10 + c];
  }
  float mx = acc[0];
#pragma unroll
  for (int c = 1; c < 10; c++) mx = fmaxf(mx, acc[c]);
  float se = 0.f;
#pragma unroll
  for (int c = 0; c < 10; c++) se += expf(acc[c] - mx);
  float lz = mx + logf(se);
#pragma unroll
  for (int c = 0; c < 10; c++) out[(size_t)r * 10 + c] = acc[c] - lz;
}

// plain final for Plan B
__global__ __launch_bounds__(256) void final_kernel(const float* __restrict__ h2,
                                                    const float* __restrict__ Wl,
                                                    const float* __restrict__ bl,
                                                    float* __restrict__ out, int N) {
  __shared__ float Ws[3000];
  for (int i = threadIdx.x; i < 3000; i += 256) Ws[i] = Wl[i];
  __syncthreads();
  int r = blockIdx.x * blockDim.x + threadIdx.x;
  if (r >= N) return;
  float acc[10];
#pragma unroll
  for (int c = 0; c < 10; c++) acc[c] = bl[c];
  const float* hr = h2 + (size_t)r * 300;
  for (int k = 0; k < 300; k++) {
    float x = hr[k];
#pragma unroll
    for (int c = 0; c < 10; c++) acc[c] += x * Ws[k * 10 + c];
  }
  float mx = acc[0];
#pragma unroll
  for (int c = 1; c < 10; c++) mx = fmaxf(mx, acc[c]);
  float se = 0.f;
#pragma unroll
  for (int c = 0; c < 10; c++) se += expf(acc[c] - mx);
  float lz = mx + logf(se);
#pragma unroll
  for (int c = 0; c < 10; c++) out[(size_t)r * 10 + c] = acc[c] - lz;
}

// ================= PLAN B (fp32 fallback, known-good) =================

__global__ void prop_kernel(const float* __restrict__ src, int srcLd4, int D4,
                            const int* __restrict__ off, const int2* __restrict__ ePack,
                            float* __restrict__ dst, int dstLd4,
                            const float* __restrict__ sub, int subLd4, float scale) {
  int v = blockIdx.x;
  int f4 = threadIdx.x;
  if (f4 >= D4) return;
  int s = off[v], e = off[v + 1];
  float ax = 0.f, ay = 0.f, az = 0.f, aw = 0.f;
  for (int i = s; i < e; i++) {
    int2 p = ePack[i];
    float w = __int_as_float(p.y);
    const float4 hv = *reinterpret_cast<const float4*>(src + ((size_t)p.x * srcLd4 + f4) * 4);
    ax += w * hv.x; ay += w * hv.y; az += w * hv.z; aw += w * hv.w;
  }
  float4 o;
  if (sub) {
    const float4 sv = *reinterpret_cast<const float4*>(sub + ((size_t)v * subLd4 + f4) * 4);
    o.x = scale * ax - sv.x; o.y = scale * ay - sv.y;
    o.z = scale * az - sv.z; o.w = scale * aw - sv.w;
  } else {
    o.x = ax; o.y = ay; o.z = az; o.w = aw;
  }
  *reinterpret_cast<float4*>(dst + ((size_t)v * dstLd4 + f4) * 4) = o;
}

#define BM 64
#define BN 64
#define BK 16

__global__ __launch_bounds__(256) void gemm_kernel(
    const float* __restrict__ A, int lda,
    const float* __restrict__ B, int ldb,
    float* __restrict__ C, int ldc, int c0,
    int M, int Nc, int K,
    const float* __restrict__ bias, int accumulate) {
  __shared__ float As[BK][BM + 4];
  __shared__ float Bs[BK][BN + 4];
  int tid = threadIdx.x;
  int tx = tid & 15, ty = tid >> 4;
  int row0 = blockIdx.y * BM, col0 = blockIdx.x * BN;
  float acc[4][4] = {};
  int aM = tid >> 2;
  int aK = (tid & 3) << 2;
  int bK = tid >> 4;
  int bN = (tid & 15) << 2;
  for (int k0 = 0; k0 < K; k0 += BK) {
    float4 av = make_float4(0.f, 0.f, 0.f, 0.f);
    int ar = row0 + aM;
    if (ar < M && k0 + aK < K)
      av = *reinterpret_cast<const float4*>(A + (size_t)ar * lda + k0 + aK);
    As[aK + 0][aM] = av.x; As[aK + 1][aM] = av.y;
    As[aK + 2][aM] = av.z; As[aK + 3][aM] = av.w;
    float4 bv = make_float4(0.f, 0.f, 0.f, 0.f);
    int bc = col0 + bN;
    if (bc < Nc && k0 + bK < K)
      bv = *reinterpret_cast<const float4*>(B + (size_t)(k0 + bK) * ldb + bc);
    Bs[bK][bN + 0] = bv.x; Bs[bK][bN + 1] = bv.y;
    Bs[bK][bN + 2] = bv.z; Bs[bK][bN + 3] = bv.w;
    __syncthreads();
#pragma unroll
    for (int k = 0; k < BK; k++) {
      float a0 = As[k][ty * 4 + 0], a1 = As[k][ty * 4 + 1];
      float a2 = As[k][ty * 4 + 2], a3 = As[k][ty * 4 + 3];
      float b0 = Bs[k][tx * 4 + 0], b1 = Bs[k][tx * 4 + 1];
      float b2 = Bs[k][tx * 4 + 2], b3 = Bs[k][tx * 4 + 3];
      acc[0][0] += a0 * b0; acc[0][1] += a0 * b1; acc[0][2] += a0 * b2; acc[0][3] += a0 * b3;
      acc[1][0] += a1 * b0; acc[1][1] += a1 * b1; acc[1][2] += a1 * b2; acc[1][3] += a1 * b3;
      acc[2][0] += a2 * b0; acc[2][1] += a2 * b1; acc[2][2] += a2 * b2; acc[2][3] += a2 * b3;
      acc[3][0] += a3 * b0; acc[3][1] += a3 * b1; acc[3][2] += a3 * b2; acc[3][3] += a3 * b3;
    }
    __syncthreads();
  }
#pragma unroll
  for (int i = 0; i < 4; i++) {
    int r = row0 + ty * 4 + i;
    if (r >= M) continue;
#pragma unroll
    for (int j = 0; j < 4; j++) {
      int c = col0 + tx * 4 + j;
      if (c >= Nc) continue;
      float v = acc[i][j];
      if (bias) v += bias[c];
      float* p = C + (size_t)r * ldc + c0 + c;
      if (accumulate) *p += v; else *p = v;
    }
  }
}

// ---------------- launch ----------------

static inline int gemm_grid_ct(int M, int colTiles) {
  int rowTiles = (M + 127) >> 7;
  int rpx = (rowTiles + 7) >> 3;
  return 8 * rpx * colTiles;
}

extern "C" void kernel_launch(void* const* d_in, const int* in_sizes, int n_in,
                              void* d_out, int out_size, void* d_ws, size_t ws_size,
                              hipStream_t stream) {
  const float* x   = (const float*)d_in[0];
  const int*   ei  = (const int*)d_in[1];
  const float* ew  = (const float*)d_in[2];
  const float* W1a = (const float*)d_in[3];
  const float* b1a = (const float*)d_in[4];
  const float* W1b = (const float*)d_in[5];
  const float* b1b = (const float*)d_in[6];
  const float* W1c = (const float*)d_in[7];
  const float* b1c = (const float*)d_in[8];
  const float* g1  = (const float*)d_in[9];
  const float* be1 = (const float*)d_in[10];
  const float* W2a = (const float*)d_in[11];
  const float* b2a = (const float*)d_in[12];
  const float* W2b = (const float*)d_in[13];
  const float* b2b = (const float*)d_in[14];
  const float* W2c = (const float*)d_in[15];
  const float* b2c = (const float*)d_in[16];
  const float* g2  = (const float*)d_in[17];
  const float* be2 = (const float*)d_in[18];
  const float* Wl  = (const float*)d_in[19];
  const float* bl  = (const float*)d_in[20];
  float* out = (float*)d_out;

  const int N = in_sizes[0] / 512;
  const int E = in_sizes[1] / 2;
  const int* row = ei;
  const int* col = ei + E;
  (void)n_in; (void)out_size;

  int eb = (E + 255) / 256;
  int nb = (N + 255) / 256;
  int nb1 = (N + 1023) / 1024;

  // ---- common prefix layout ----
  char* ws = (char*)d_ws;
  size_t o = 0;
  int2*  ePack = (int2*)(ws + o);  o += (size_t)E * 8;
  float* dis   = (float*)(ws + o); o += (size_t)N * 4;
  int*   cnt   = (int*)(ws + o);   o += (size_t)N * 4;
  int*   off   = (int*)(ws + o);   o += (size_t)(N + 4) * 4;
  int*   wptr  = (int*)(ws + o);   o += (size_t)N * 4;
  int*   bsum  = (int*)(ws + o);   o += (size_t)(nb1 + 4) * 4;
  float* sums  = (float*)(ws + o); o += 2400 * 4;
  float* scSh  = (float*)(ws + o); o += 2400 * 4;
  float* bcat1 = (float*)(ws + o); o += 1200 * 4;
  float* bcat2 = (float*)(ws + o); o += 304 * 4;
  o = (o + 255) & ~(size_t)255;
  size_t oCommon = o;

  // ---- plan A layout ----
  size_t oA = oCommon;
  unsigned short* BtL1 = (unsigned short*)(ws + oA); oA += (size_t)1280 * 1536 * 2;
  unsigned short* BtL2 = (unsigned short*)(ws + oA); oA += (size_t)640 * 1216 * 2;
  oA = (oA + 255) & ~(size_t)255;
  unsigned short* h1n = (unsigned short*)(ws + oA); oA += (size_t)N * 1216 * 2;
  oA = (oA + 255) & ~(size_t)255;
  float* h2f = (float*)(ws + oA); oA += (size_t)N * 300 * 4;
  oA = (oA + 255) & ~(size_t)255;
  // region X: Xcat (N x 1536 bf16) in phase 1; Zcat (N x 304) + U1 (N x 104) in phase 2
  unsigned short* Xcat = (unsigned short*)(ws + oA); oA += (size_t)N * 1536 * 2;
  unsigned short* Zcat = Xcat;
  unsigned short* U1 = Xcat + (size_t)N * 304;

  bool planA = (ws_size >= oA);

  // ---- graph prep (both plans) ----
  hipMemsetAsync(dis, 0, (size_t)N * 4, stream);
  hipMemsetAsync(cnt, 0, (size_t)N * 4, stream);
  degcnt_kernel<<<eb, 256, 0, stream>>>(row, col, ew, dis, cnt, E);
  dis_kernel<<<nb, 256, 0, stream>>>(dis, N);
  scan1_kernel<<<nb1, 1024, 0, stream>>>(cnt, off, bsum, N);
  scan2_kernel<<<1, 64, 0, stream>>>(bsum, off, nb1, N);
  scan3_kernel<<<nb, 256, 0, stream>>>(off, bsum, N);
  copy_kernel<<<nb, 256, 0, stream>>>(off, wptr, N);
  fill_kernel<<<eb, 256, 0, stream>>>(row, col, ew, dis, wptr, ePack, E);

  if (planA) {
    // fused weight prep:
    // BtL1 [1280 x 1536]: rows 0-399 W1a (K 0-512), 400-799 W1b (K 0-1024),
    //                     800-1199 W1c (K 0-1536); rest zero.
    // BtL2 [640 x 1216]:  rows 0-99 W2a k0, 100-199 W2b k0, 200-299 W2c k0,
    //                     304-403 W2b k1, 404-503 W2c k1, 504-603 W2c k2; rest zero.
    hipMemsetAsync(BtL1, 0, (size_t)1280 * 1536 * 2, stream);
    hipMemsetAsync(BtL2, 0, (size_t)640 * 1216 * 2, stream);
    wprep_kernel<<<(400 * 512 + 255) / 256, 256, 0, stream>>>(W1a, BtL1, 512, 400, 1536, 0);
    wprep_kernel<<<(400 * 1024 + 255) / 256, 256, 0, stream>>>(W1b, BtL1, 1024, 400, 1536, 400);
    wprep_kernel<<<(400 * 1536 + 255) / 256, 256, 0, stream>>>(W1c, BtL1, 1536, 400, 1536, 800);
    wprep_kernel<<<(100 * 1200 + 255) / 256, 256, 0, stream>>>(W2a, BtL2, 1200, 100, 1216, 0);
    wprep_kernel<<<(100 * 1200 + 255) / 256, 256, 0, stream>>>(W2b, BtL2, 1200, 100, 1216, 100);
    wprep_kernel<<<(100 * 1200 + 255) / 256, 256, 0, stream>>>(W2c, BtL2, 1200, 100, 1216, 200);
    wprep_kernel<<<(100 * 1200 + 255) / 256, 256, 0, stream>>>(W2b + 1200 * 100, BtL2, 1200, 100, 1216, 304);
    wprep_kernel<<<(100 * 1200 + 255) / 256, 256, 0, stream>>>(W2c + 1200 * 100, BtL2, 1200, 100, 1216, 404);
    wprep_kernel<<<(100 * 1200 + 255) / 256, 256, 0, stream>>>(W2c + 2 * 1200 * 100, BtL2, 1200, 100, 1216, 504);
    bcat_kernel<<<(1200 + 255) / 256, 256, 0, stream>>>(b1a, b1b, b1c, bcat1, 400);
    bcat_kernel<<<(300 + 255) / 256, 256, 0, stream>>>(b2a, b2b, b2c, bcat2, 100);
    cast_x_kernel<<<(N * 128 + 255) / 256, 256, 0, stream>>>(x, Xcat, N);
    padzero_kernel<<<(N * 2 + 255) / 256, 256, 0, stream>>>(h1n, N);

    // layer-1 props (XCD-affine chunked): P1 = L x ; P2 = 2 L P1 - x
    int gridP = ((N + 7) / 8) * 8;
    prop_chunk_kernel<<<gridP, 256, 0, stream>>>(Xcat, 1536, 0, 512, -1,
                                                 off, ePack, 1.f, N);
    prop_chunk_kernel<<<gridP, 256, 0, stream>>>(Xcat, 1536, 512, 1024, 0,
                                                 off, ePack, 2.f, N);

    // layer-1 fused GEMM -> h1n (bf16, ld 1216), per-col-tile K
    gemm_l1_kernel<<<gemm_grid_ct(N, 10), 256, 0, stream>>>(Xcat, BtL1, N, bcat1, h1n);

    // BN1 + ReLU on h1n
    hipMemsetAsync(sums, 0, 2400 * 4, stream);
    dim3 s1g((1200 + 255) / 256, (N + 255) / 256);
    bn_stats_bf16_kernel<<<s1g, 256, 0, stream>>>(h1n, 1216, 1200, N, sums);
    scsh_kernel<<<(1200 + 255) / 256, 256, 0, stream>>>(sums, g1, be1, 1.f / (float)N, 1200, scSh);
    bn_apply_bf16_kernel<<<((size_t)N * 150 + 255) / 256, 256, 0, stream>>>(
        h1n, 1216, 150, N, scSh, 1200, 1);

    // layer-2 fused GEMM: cols 0-299 -> h2f fp32 (+bias), cols 304-607 -> Zcat bf16
    gemm_l2_kernel<<<gemm_grid_ct(N, 5), 256, 0, stream>>>(h1n, BtL2, N, bcat2, Zcat, h2f);

    // commuted props
    prop_z_kernel<<<N, 64, 0, stream>>>(Zcat, off, ePack, h2f, U1);
    prop_u_kernel<<<N, 64, 0, stream>>>(U1, off, ePack, Zcat, h2f);

    // BN2 stats -> scSh; apply fused into final
    hipMemsetAsync(sums, 0, 2400 * 4, stream);
    dim3 s2g((300 + 255) / 256, (N + 255) / 256);
    bn_stats_kernel<<<s2g, 256, 0, stream>>>(h2f, 300, N, sums);
    scsh_kernel<<<(300 + 255) / 256, 256, 0, stream>>>(sums, g2, be2, 1.f / (float)N, 300, scSh);
    final_bn_kernel<<<nb, 256, 0, stream>>>(h2f, scSh, Wl, bl, out, N);
    return;
  }

  // ================= PLAN B (fp32 fallback) =================
  size_t oB = oCommon;
  float* h2 = (float*)(ws + oB); oB += (size_t)N * 300 * 4;
  oB = (oB + 255) & ~(size_t)255;
  float* h1 = (float*)(ws + oB); oB += (size_t)N * 1200 * 4;
  oB = (oB + 255) & ~(size_t)255;
  size_t avail = (ws_size > oB) ? (ws_size - oB) : 0;
  int C1 = 64;
  { const int opts[4] = {512, 256, 128, 64};
    for (int i = 0; i < 4; i++)
      if ((size_t)2 * N * opts[i] * 4 <= avail) { C1 = opts[i]; break; } }
  int C2 = 100;
  { const int opts[6] = {1200, 600, 400, 300, 200, 100};
    for (int i = 0; i < 6; i++)
      if ((size_t)2 * N * opts[i] * 4 <= avail) { C2 = opts[i]; break; } }
  int maxC = C1 > C2 ? C1 : C2;
  float* S1 = (float*)(ws + oB);
  float* S2 = S1 + (size_t)N * maxC;

  dim3 g1d((400 + BN - 1) / BN, (N + BM - 1) / BM);
  gemm_kernel<<<g1d, 256, 0, stream>>>(x, 512, W1a, 400, h1, 1200, 0,   N, 400, 512, b1a, 0);
  gemm_kernel<<<g1d, 256, 0, stream>>>(x, 512, W1b, 400, h1, 1200, 400, N, 400, 512, b1b, 0);
  gemm_kernel<<<g1d, 256, 0, stream>>>(x, 512, W1c, 400, h1, 1200, 800, N, 400, 512, b1c, 0);
  for (int c = 0; c < 512; c += C1) {
    int D4 = C1 / 4;
    int bt = ((D4 + 63) / 64) * 64;
    prop_kernel<<<N, bt, 0, stream>>>(x + c, 128, D4, off, ePack, S1, D4, nullptr, 0, 1.f);
    gemm_kernel<<<g1d, 256, 0, stream>>>(S1, C1, W1b + (size_t)(512 + c) * 400, 400, h1, 1200, 400, N, 400, C1, nullptr, 1);
    gemm_kernel<<<g1d, 256, 0, stream>>>(S1, C1, W1c + (size_t)(512 + c) * 400, 400, h1, 1200, 800, N, 400, C1, nullptr, 1);
    prop_kernel<<<N, bt, 0, stream>>>(S1, D4, D4, off, ePack, S2, D4, x + c, 128, 2.f);
    gemm_kernel<<<g1d, 256, 0, stream>>>(S2, C1, W1c + (size_t)(2 * 512 + c) * 400, 400, h1, 1200, 800, N, 400, C1, nullptr, 1);
  }

  hipMemsetAsync(sums, 0, 2400 * 4, stream);
  dim3 s1g((1200 + 255) / 256, (N + 255) / 256);
  bn_stats_kernel<<<s1g, 256, 0, stream>>>(h1, 1200, N, sums);
  dim3 a1g((300 + 63) / 64, (N + 255) / 256);
  bn_apply_kernel<<<a1g, 64, 0, stream>>>(h1, 1200, N, sums, g1, be1, 1.f / (float)N, 1);

  dim3 g2d((100 + BN - 1) / BN, (N + BM - 1) / BM);
  gemm_kernel<<<g2d, 256, 0, stream>>>(h1, 1200, W2a, 100, h2, 300, 0,   N, 100, 1200, b2a, 0);
  gemm_kernel<<<g2d, 256, 0, stream>>>(h1, 1200, W2b, 100, h2, 300, 100, N, 100, 1200, b2b, 0);
  gemm_kernel<<<g2d, 256, 0, stream>>>(h1, 1200, W2c, 100, h2, 300, 200, N, 100, 1200, b2c, 0);
  for (int c = 0; c < 1200; c += C2) {
    int D4 = C2 / 4;
    int bt = ((D4 + 63) / 64) * 64;
    prop_kernel<<<N, bt, 0, stream>>>(h1 + c, 300, D4, off, ePack, S1, D4, nullptr, 0, 1.f);
    gemm_kernel<<<g2d, 256, 0, stream>>>(S1, C2, W2b + (size_t)(1200 + c) * 100, 100, h2, 300, 100, N, 100, C2, nullptr, 1);
    gemm_kernel<<<g2d, 256, 0, stream>>>(S1, C2, W2c + (size_t)(1200 + c) * 100, 100, h2, 300, 200, N, 100, C2, nullptr, 1);
    prop_kernel<<<N, bt, 0, stream>>>(S1, D4, D4, off, ePack, S2, D4, h1 + c, 300, 2.f);
    gemm_kernel<<<g2d, 256, 0, stream>>>(S2, C2, W2c + (size_t)(2 * 1200 + c) * 100, 100, h2, 300, 200, N, 100, C2, nullptr, 1);
  }

  hipMemsetAsync(sums, 0, 2400 * 4, stream);
  dim3 s2g((300 + 255) / 256, (N + 255) / 256);
  bn_stats_kernel<<<s2g, 256, 0, stream>>>(h2, 300, N, sums);
  dim3 a2g((75 + 63) / 64, (N + 255) / 256);
  bn_apply_kernel<<<a2g, 64, 0, stream>>>(h2, 300, N, sums, g2, be2, 1.f / (float)N, 0);

  final_kernel<<<nb, 256, 0, stream>>>(h2, Wl, bl, out, N);
}